// Round 5
// baseline (293.713 us; speedup 1.0000x reference)
//
#include <hip/hip_runtime.h>
#include <stdint.h>

// Problem constants
#define S_LEN 2048
#define EMB   1024
#define NH    16
#define DK    64
#define BATCH 2
#define MTOT  (BATCH * S_LEN)  // 4096

typedef __attribute__((ext_vector_type(8))) short    short8;
typedef __attribute__((ext_vector_type(4))) float    f32x4;
typedef __attribute__((ext_vector_type(4))) float    float4v;
typedef __attribute__((ext_vector_type(4))) unsigned uint4v;
typedef __attribute__((ext_vector_type(2))) unsigned uint2v;

__device__ __forceinline__ short f2b(float f) {
  unsigned u = __builtin_bit_cast(unsigned, f);
  u = (u + 0x7FFFu + ((u >> 16) & 1u)) >> 16;  // RNE to bf16
  return (short)u;
}
// pack two f32 -> two bf16 in one uint (low = a, high = b)
__device__ __forceinline__ unsigned cvt2(float a, float b) {
  unsigned r;
  asm("v_cvt_pk_bf16_f32 %0, %1, %2" : "=v"(r) : "v"(a), "v"(b));
  return r;
}

// ---------------------------------------------------------------------------
// f32 -> bf16 bulk convert (weights pre-pass). n4 = count/4.
// ---------------------------------------------------------------------------
__global__ __launch_bounds__(256) void cvt_f32_bf16(const float* __restrict__ src,
                                                    short* __restrict__ dst, int n4)
{
  const int i = blockIdx.x * blockDim.x + threadIdx.x;
  if (i < n4) {
    const f32x4 v = *(const f32x4*)(src + (size_t)i * 4);
    uint2v p;
    p[0] = cvt2(v[0], v[1]);
    p[1] = cvt2(v[2], v[3]);
    *(uint2v*)(dst + (size_t)i * 4) = p;
  }
}

// ---------------------------------------------------------------------------
// NT GEMM: C(M x N) = A(M x K) * W(N x K)^T + bias. M=4096, N=1024, K=1024.
// W = bf16 (pre-converted). Tile 128x128, BK=64, 256 threads (4 waves 2x2,
// each wave 64x64 = 4x4 MFMA frags). LDS k-chunk-major [chunk8][row128][16B]
// -> each fragment read is one contiguous ds_read_b128 per lane.
// Grid: 1D 256 blocks, XCD-swizzled so the 8 N-blocks sharing an A-panel
// live on one XCD (A panel 512KB f32, 4 panels + W 2MB fit the 4MB L2).
// MODE 0: A = f32 (cvt to bf16 in staging); out = bf16 scattered (B,H,S,DK).
// MODE 1: A = bf16; out = f32 row-major (M,N).
// ---------------------------------------------------------------------------
template <int MODE>
__global__ __launch_bounds__(256) void gemm_nt(const void* __restrict__ Av,
                                               const short* __restrict__ W,
                                               const float* __restrict__ bias,
                                               void* __restrict__ outv,
                                               float scale)
{
  __shared__ __align__(16) unsigned Au[8][128][4];  // 16 KB
  __shared__ __align__(16) unsigned Bu[8][128][4];  // 16 KB
  const int tid = threadIdx.x;
  const int w = tid >> 6, l = tid & 63;
  const int g = l >> 4, r16 = l & 15;
  // XCD swizzle: 256 blocks, 8 XCDs -> each XCD gets 4 consecutive M-rows.
  const int lin = (blockIdx.x & 7) * 32 + (blockIdx.x >> 3);
  const int m0 = (lin >> 3) * 128, n0 = (lin & 7) * 128;
  const int wr = w >> 1, wc = w & 1;       // wave tile 64x64 at (wr*64, wc*64)
  const int srow = tid >> 3, shc = tid & 7;

  float4v acc[4][4];
#pragma unroll
  for (int i = 0; i < 4; ++i)
#pragma unroll
    for (int j = 0; j < 4; ++j)
      acc[i][j] = (float4v){0.f, 0.f, 0.f, 0.f};

  const float* Af = (const float*)Av + (size_t)m0 * EMB;
  const short* Ab = (const short*)Av + (size_t)m0 * EMB;
  const short* Wbase = W + (size_t)n0 * EMB;

  for (int k0 = 0; k0 < EMB; k0 += 64) {
    uint4v apk[4], bpk[4];
    if constexpr (MODE == 0) {
#pragma unroll
      for (int p = 0; p < 4; ++p) {
        const float* src = Af + (size_t)(p * 32 + srow) * EMB + k0 + shc * 8;
        const f32x4 x = *(const f32x4*)src;
        const f32x4 y = *(const f32x4*)(src + 4);
        apk[p][0] = cvt2(x[0], x[1]);
        apk[p][1] = cvt2(x[2], x[3]);
        apk[p][2] = cvt2(y[0], y[1]);
        apk[p][3] = cvt2(y[2], y[3]);
      }
    } else {
#pragma unroll
      for (int p = 0; p < 4; ++p)
        apk[p] = __builtin_bit_cast(uint4v,
            *(const short8*)(Ab + (size_t)(p * 32 + srow) * EMB + k0 + shc * 8));
    }
#pragma unroll
    for (int p = 0; p < 4; ++p)
      bpk[p] = __builtin_bit_cast(uint4v,
          *(const short8*)(Wbase + (size_t)(p * 32 + srow) * EMB + k0 + shc * 8));

    __syncthreads();
#pragma unroll
    for (int p = 0; p < 4; ++p)
      *(uint4v*)&Au[shc][p * 32 + srow][0] = apk[p];
#pragma unroll
    for (int p = 0; p < 4; ++p)
      *(uint4v*)&Bu[shc][p * 32 + srow][0] = bpk[p];
    __syncthreads();

#pragma unroll
    for (int ks = 0; ks < 2; ++ks) {
      const int c = ks * 4 + g;
      short8 af[4], bf[4];
#pragma unroll
      for (int i = 0; i < 4; ++i)
        af[i] = __builtin_bit_cast(short8, *(const uint4v*)&Au[c][wr * 64 + i * 16 + r16][0]);
#pragma unroll
      for (int j = 0; j < 4; ++j)
        bf[j] = __builtin_bit_cast(short8, *(const uint4v*)&Bu[c][wc * 64 + j * 16 + r16][0]);
#pragma unroll
      for (int i = 0; i < 4; ++i)
#pragma unroll
        for (int j = 0; j < 4; ++j)
          acc[i][j] = __builtin_amdgcn_mfma_f32_16x16x32_bf16(af[i], bf[j], acc[i][j], 0, 0, 0);
    }
  }

  // Epilogue: C/D layout is col = l&15, row = (l>>4)*4 + r
#pragma unroll
  for (int j = 0; j < 4; ++j) {
    const int n = n0 + wc * 64 + j * 16 + r16;
    const float bv = bias[n];
#pragma unroll
    for (int i = 0; i < 4; ++i) {
#pragma unroll
      for (int r = 0; r < 4; ++r) {
        const int m = m0 + wr * 64 + i * 16 + g * 4 + r;
        const float vv = (acc[i][j][r] + bv) * scale;
        if constexpr (MODE == 0) {
          const int b = m >> 11, s = m & (S_LEN - 1);
          const int h = n >> 6, d = n & (DK - 1);
          ((short*)outv)[(size_t)((b * NH + h) * S_LEN + s) * DK + d] = f2b(vv);
        } else {
          ((float*)outv)[(size_t)m * EMB + n] = vv;
        }
      }
    }
  }
}

// ---------------------------------------------------------------------------
// Flash attention (bf16 in/out, f32 softmax+acc). 1D grid of 1024 blocks,
// XCD-swizzled so each XCD works 4 (b,h) pairs (K/V = 2MB, L2-resident).
// Block 256 = 4 waves, wave handles 16 q rows. Swapped QK^T: S^T =
// mfma(K_frag, Q_frag) -> lane holds q = l&15, kv = (l>>4)*4 + r. Softmax
// reduce = in-lane + shfl_xor 16/32. V^T staged with conflict-free writes
// (loader: kv pair = tid&31 -> bank = lane&31). P is per-wave (no barrier).
// Scores pre-scaled via Q projection (x0.125).
// ---------------------------------------------------------------------------
__global__ __launch_bounds__(256) void attn_kernel(const short* __restrict__ Qp,
                                                   const short* __restrict__ Kp,
                                                   const short* __restrict__ Vp,
                                                   short* __restrict__ ctx)
{
  __shared__ __align__(16) unsigned Vtu[64][36];     // V^T tile [d][kv pair]
  __shared__ __align__(16) unsigned Plu[4][16][36];  // per-wave P [q][kv pair]
  const int tid = threadIdx.x;
  const int w = tid >> 6, l = tid & 63;
  const int g = l >> 4, r16 = l & 15;
  const int lin = (blockIdx.x & 7) * 128 + (blockIdx.x >> 3);
  const int bh = lin >> 5;                         // b*NH + h (4 per XCD)
  const int q0 = (lin & 31) * 64 + w * 16;
  const short* Qb = Qp + (size_t)bh * S_LEN * DK;
  const short* Kb = Kp + (size_t)bh * S_LEN * DK;
  const short* Vb = Vp + (size_t)bh * S_LEN * DK;

  const short8 qf0 = *(const short8*)(Qb + (size_t)(q0 + r16) * DK + g * 8);
  const short8 qf1 = *(const short8*)(Qb + (size_t)(q0 + r16) * DK + 32 + g * 8);

  float4v oacc[4];
#pragma unroll
  for (int j = 0; j < 4; ++j) oacc[j] = (float4v){0.f, 0.f, 0.f, 0.f};
  float m_run = -3.0e38f, l_run = 0.f;

  const int vkvp = tid & 31;          // kv pair -> LDS bank (conflict-free)
  const int vdc  = (tid >> 5) * 8;    // d chunk base

  for (int kv0 = 0; kv0 < S_LEN; kv0 += 64) {
    const short8 v0 = *(const short8*)(Vb + (size_t)(kv0 + 2 * vkvp) * DK + vdc);
    const short8 v1 = *(const short8*)(Vb + (size_t)(kv0 + 2 * vkvp + 1) * DK + vdc);
    __syncthreads();  // prior iteration's Vtu reads complete
#pragma unroll
    for (int i = 0; i < 8; ++i) {
      unsigned pk = ((unsigned)(unsigned short)v0[i]) |
                    (((unsigned)(unsigned short)v1[i]) << 16);
      Vtu[vdc + i][vkvp] = pk;
    }
    __syncthreads();

    // --- S^T = K * Q^T for four 16-kv subtiles ---
    float4v st[4];
#pragma unroll
    for (int s = 0; s < 4; ++s) {
      const short8 kf0 = *(const short8*)(Kb + (size_t)(kv0 + s * 16 + r16) * DK + g * 8);
      const short8 kf1 = *(const short8*)(Kb + (size_t)(kv0 + s * 16 + r16) * DK + 32 + g * 8);
      float4v a = (float4v){0.f, 0.f, 0.f, 0.f};
      a = __builtin_amdgcn_mfma_f32_16x16x32_bf16(kf0, qf0, a, 0, 0, 0);
      a = __builtin_amdgcn_mfma_f32_16x16x32_bf16(kf1, qf1, a, 0, 0, 0);
      st[s] = a;
    }

    // --- online softmax (per lane: q = l&15, 16 kv values) ---
    float mt = -3.0e38f;
#pragma unroll
    for (int s = 0; s < 4; ++s)
#pragma unroll
      for (int r = 0; r < 4; ++r) mt = fmaxf(mt, st[s][r]);
    mt = fmaxf(mt, __shfl_xor(mt, 16));
    mt = fmaxf(mt, __shfl_xor(mt, 32));
    const float m_new = fmaxf(m_run, mt);
    const float alpha = __expf(m_run - m_new);
    float psum = 0.f;
#pragma unroll
    for (int s = 0; s < 4; ++s)
#pragma unroll
      for (int r = 0; r < 4; ++r) {
        const float p = __expf(st[s][r] - m_new);
        st[s][r] = p;
        psum += p;
      }
    l_run = l_run * alpha + psum;
    m_run = m_new;

    // --- P -> per-wave LDS (v_cvt_pk packing; same-wave RAW, no barrier) ---
#pragma unroll
    for (int s = 0; s < 4; ++s) {
      Plu[w][r16][s * 8 + g * 2]     = cvt2(st[s][0], st[s][1]);
      Plu[w][r16][s * 8 + g * 2 + 1] = cvt2(st[s][2], st[s][3]);
    }

    // --- rescale O by alpha ---
    const float ar0 = __shfl(alpha, g * 4 + 0);
    const float ar1 = __shfl(alpha, g * 4 + 1);
    const float ar2 = __shfl(alpha, g * 4 + 2);
    const float ar3 = __shfl(alpha, g * 4 + 3);
#pragma unroll
    for (int j = 0; j < 4; ++j) {
      oacc[j][0] *= ar0; oacc[j][1] *= ar1;
      oacc[j][2] *= ar2; oacc[j][3] *= ar3;
    }

    // --- PV: O += P(16x64) * V(64x64) ---
#pragma unroll
    for (int kc = 0; kc < 2; ++kc) {
      const short8 pf = __builtin_bit_cast(short8, *(const uint4v*)&Plu[w][r16][kc * 16 + g * 4]);
#pragma unroll
      for (int j = 0; j < 4; ++j) {
        const short8 vf = __builtin_bit_cast(short8, *(const uint4v*)&Vtu[j * 16 + r16][kc * 16 + g * 4]);
        oacc[j] = __builtin_amdgcn_mfma_f32_16x16x32_bf16(pf, vf, oacc[j], 0, 0, 0);
      }
    }
  }

  // --- finalize ---
  float lt = l_run + __shfl_xor(l_run, 16);
  lt = lt + __shfl_xor(lt, 32);
  const float li0 = 1.f / __shfl(lt, g * 4 + 0);
  const float li1 = 1.f / __shfl(lt, g * 4 + 1);
  const float li2 = 1.f / __shfl(lt, g * 4 + 2);
  const float li3 = 1.f / __shfl(lt, g * 4 + 3);
  const int b = bh >> 4, h = bh & 15;
#pragma unroll
  for (int j = 0; j < 4; ++j) {
    const int d = h * DK + j * 16 + r16;
    const int qr = q0 + g * 4;
    ctx[(size_t)(b * S_LEN + qr + 0) * EMB + d] = f2b(oacc[j][0] * li0);
    ctx[(size_t)(b * S_LEN + qr + 1) * EMB + d] = f2b(oacc[j][1] * li1);
    ctx[(size_t)(b * S_LEN + qr + 2) * EMB + d] = f2b(oacc[j][2] * li2);
    ctx[(size_t)(b * S_LEN + qr + 3) * EMB + d] = f2b(oacc[j][3] * li3);
  }
}

// ---------------------------------------------------------------------------
extern "C" void kernel_launch(void* const* d_in, const int* in_sizes, int n_in,
                              void* d_out, int out_size, void* d_ws, size_t ws_size,
                              hipStream_t stream)
{
  const float* q  = (const float*)d_in[0];
  const float* k  = (const float*)d_in[1];
  const float* v  = (const float*)d_in[2];
  const float* Wq = (const float*)d_in[3];
  const float* bq = (const float*)d_in[4];
  const float* Wk = (const float*)d_in[5];
  const float* bk = (const float*)d_in[6];
  const float* Wv = (const float*)d_in[7];
  const float* bv = (const float*)d_in[8];
  const float* Wo = (const float*)d_in[9];
  const float* bo = (const float*)d_in[10];

  short* ws = (short*)d_ws;
  const size_t WSZ  = (size_t)EMB * EMB;   // 1M elems per weight matrix
  const size_t PROJ = (size_t)MTOT * EMB;  // 4M elems per activation
  short* Wqb = ws;                 // bf16 weights: 4 x 2 MB
  short* Wkb = ws + WSZ;
  short* Wvb = ws + 2 * WSZ;
  short* Wob = ws + 3 * WSZ;
  short* Qp  = ws + 4 * WSZ;       // (B,H,S,DK) bf16, pre-scaled by 1/8
  short* Vp  = Qp + PROJ;
  short* Cx  = Vp + PROJ;          // (B*S, E) bf16 context
  short* Kp  = (short*)d_out;      // K parks in d_out (8.4 MB bf16 in 16.8 MB
                                   // f32 buffer); consumed before final GEMM.

  const int n4 = (int)(WSZ / 4);
  dim3 cg((n4 + 255) / 256), cb(256);
  cvt_f32_bf16<<<cg, cb, 0, stream>>>(Wq, Wqb, n4);
  cvt_f32_bf16<<<cg, cb, 0, stream>>>(Wk, Wkb, n4);
  cvt_f32_bf16<<<cg, cb, 0, stream>>>(Wv, Wvb, n4);
  cvt_f32_bf16<<<cg, cb, 0, stream>>>(Wo, Wob, n4);

  dim3 gb(256), tb(256);  // 1D, XCD-swizzled in-kernel
  gemm_nt<0><<<gb, tb, 0, stream>>>(q, Wqb, bq, Qp, 0.125f);  // scale folded
  gemm_nt<0><<<gb, tb, 0, stream>>>(k, Wkb, bk, Kp, 1.0f);
  gemm_nt<0><<<gb, tb, 0, stream>>>(v, Wvb, bv, Vp, 1.0f);
  attn_kernel<<<dim3(1024), tb, 0, stream>>>(Qp, Kp, Vp, Cx);
  gemm_nt<1><<<gb, tb, 0, stream>>>(Cx, Wob, bo, d_out, 1.0f);
}

// Round 6
// 275.162 us; speedup vs baseline: 1.0674x; 1.0674x over previous
//
#include <hip/hip_runtime.h>
#include <stdint.h>

// Problem constants
#define S_LEN 2048
#define EMB   1024
#define NH    16
#define DK    64
#define BATCH 2
#define MTOT  (BATCH * S_LEN)  // 4096

typedef __attribute__((ext_vector_type(8))) short    short8;
typedef __attribute__((ext_vector_type(4))) float    f32x4;
typedef __attribute__((ext_vector_type(4))) float    float4v;
typedef __attribute__((ext_vector_type(4))) unsigned uint4v;
typedef __attribute__((ext_vector_type(2))) unsigned uint2v;

__device__ __forceinline__ short f2b(float f) {
  unsigned u = __builtin_bit_cast(unsigned, f);
  u = (u + 0x7FFFu + ((u >> 16) & 1u)) >> 16;  // RNE to bf16
  return (short)u;
}
// pack two f32 -> two bf16 in one uint (low = a, high = b)
__device__ __forceinline__ unsigned cvt2(float a, float b) {
  unsigned r;
  asm("v_cvt_pk_bf16_f32 %0, %1, %2" : "=v"(r) : "v"(a), "v"(b));
  return r;
}

// ---------------------------------------------------------------------------
// f32 -> bf16 bulk convert (weights pre-pass). n4 = count/4.
// ---------------------------------------------------------------------------
__global__ __launch_bounds__(256) void cvt_f32_bf16(const float* __restrict__ src,
                                                    short* __restrict__ dst, int n4)
{
  const int i = blockIdx.x * blockDim.x + threadIdx.x;
  if (i < n4) {
    const f32x4 v = *(const f32x4*)(src + (size_t)i * 4);
    uint2v p;
    p[0] = cvt2(v[0], v[1]);
    p[1] = cvt2(v[2], v[3]);
    *(uint2v*)(dst + (size_t)i * 4) = p;
  }
}

// ---------------------------------------------------------------------------
// NT GEMM (unchanged from round 5): C(MxN) = A(MxK) * W(NxK)^T + bias.
// Tile 128x128, BK=64, 256 threads (4 waves 2x2). XCD-swizzled 1D grid.
// MODE 0: A = f32 (cvt in staging); out = bf16 scattered (B,H,S,DK).
// MODE 1: A = bf16; out = f32 row-major (M,N).
// ---------------------------------------------------------------------------
template <int MODE>
__global__ __launch_bounds__(256) void gemm_nt(const void* __restrict__ Av,
                                               const short* __restrict__ W,
                                               const float* __restrict__ bias,
                                               void* __restrict__ outv,
                                               float scale)
{
  __shared__ __align__(16) unsigned Au[8][128][4];  // 16 KB
  __shared__ __align__(16) unsigned Bu[8][128][4];  // 16 KB
  const int tid = threadIdx.x;
  const int w = tid >> 6, l = tid & 63;
  const int g = l >> 4, r16 = l & 15;
  const int lin = (blockIdx.x & 7) * 32 + (blockIdx.x >> 3);
  const int m0 = (lin >> 3) * 128, n0 = (lin & 7) * 128;
  const int wr = w >> 1, wc = w & 1;
  const int srow = tid >> 3, shc = tid & 7;

  float4v acc[4][4];
#pragma unroll
  for (int i = 0; i < 4; ++i)
#pragma unroll
    for (int j = 0; j < 4; ++j)
      acc[i][j] = (float4v){0.f, 0.f, 0.f, 0.f};

  const float* Af = (const float*)Av + (size_t)m0 * EMB;
  const short* Ab = (const short*)Av + (size_t)m0 * EMB;
  const short* Wbase = W + (size_t)n0 * EMB;

  for (int k0 = 0; k0 < EMB; k0 += 64) {
    uint4v apk[4], bpk[4];
    if constexpr (MODE == 0) {
#pragma unroll
      for (int p = 0; p < 4; ++p) {
        const float* src = Af + (size_t)(p * 32 + srow) * EMB + k0 + shc * 8;
        const f32x4 x = *(const f32x4*)src;
        const f32x4 y = *(const f32x4*)(src + 4);
        apk[p][0] = cvt2(x[0], x[1]);
        apk[p][1] = cvt2(x[2], x[3]);
        apk[p][2] = cvt2(y[0], y[1]);
        apk[p][3] = cvt2(y[2], y[3]);
      }
    } else {
#pragma unroll
      for (int p = 0; p < 4; ++p)
        apk[p] = __builtin_bit_cast(uint4v,
            *(const short8*)(Ab + (size_t)(p * 32 + srow) * EMB + k0 + shc * 8));
    }
#pragma unroll
    for (int p = 0; p < 4; ++p)
      bpk[p] = __builtin_bit_cast(uint4v,
          *(const short8*)(Wbase + (size_t)(p * 32 + srow) * EMB + k0 + shc * 8));

    __syncthreads();
#pragma unroll
    for (int p = 0; p < 4; ++p)
      *(uint4v*)&Au[shc][p * 32 + srow][0] = apk[p];
#pragma unroll
    for (int p = 0; p < 4; ++p)
      *(uint4v*)&Bu[shc][p * 32 + srow][0] = bpk[p];
    __syncthreads();

#pragma unroll
    for (int ks = 0; ks < 2; ++ks) {
      const int c = ks * 4 + g;
      short8 af[4], bf[4];
#pragma unroll
      for (int i = 0; i < 4; ++i)
        af[i] = __builtin_bit_cast(short8, *(const uint4v*)&Au[c][wr * 64 + i * 16 + r16][0]);
#pragma unroll
      for (int j = 0; j < 4; ++j)
        bf[j] = __builtin_bit_cast(short8, *(const uint4v*)&Bu[c][wc * 64 + j * 16 + r16][0]);
#pragma unroll
      for (int i = 0; i < 4; ++i)
#pragma unroll
        for (int j = 0; j < 4; ++j)
          acc[i][j] = __builtin_amdgcn_mfma_f32_16x16x32_bf16(af[i], bf[j], acc[i][j], 0, 0, 0);
    }
  }

#pragma unroll
  for (int j = 0; j < 4; ++j) {
    const int n = n0 + wc * 64 + j * 16 + r16;
    const float bv = bias[n];
#pragma unroll
    for (int i = 0; i < 4; ++i) {
#pragma unroll
      for (int r = 0; r < 4; ++r) {
        const int m = m0 + wr * 64 + i * 16 + g * 4 + r;
        const float vv = (acc[i][j][r] + bv) * scale;
        if constexpr (MODE == 0) {
          const int b = m >> 11, s = m & (S_LEN - 1);
          const int h = n >> 6, d = n & (DK - 1);
          ((short*)outv)[(size_t)((b * NH + h) * S_LEN + s) * DK + d] = f2b(vv);
        } else {
          ((float*)outv)[(size_t)m * EMB + n] = vv;
        }
      }
    }
  }
}

// ---------------------------------------------------------------------------
// Flash attention, latency-hiding restructure:
//  - V and K fragments for tile t+1 register-prefetched during tile t
//  - coalesced V global loads (lane = d-chunk fastest) + XOR-swizzled V^T
//    LDS writes: col' = col ^ (((row>>3)&7)<<2)  -> 2-way write (free),
//    16B-aligned swizzled b128 reads at the bank data-volume floor
//  - double-buffered V^T tile -> ONE barrier per kv-iteration
//  - QK + softmax (all-register) before the barrier; only PV waits
// Grid 1024 blocks XCD-swizzled (4 bh per XCD, K/V L2-resident).
// Scores pre-scaled via Q projection (x0.125).
// ---------------------------------------------------------------------------
__global__ __launch_bounds__(256, 4) void attn_kernel(const short* __restrict__ Qp,
                                                      const short* __restrict__ Kp,
                                                      const short* __restrict__ Vp,
                                                      short* __restrict__ ctx)
{
  __shared__ __align__(16) unsigned Vtu[2][64][36];  // 18432 B
  __shared__ __align__(16) unsigned Plu[4][16][36];  //  9216 B
  const int tid = threadIdx.x;
  const int w = tid >> 6, l = tid & 63;
  const int g = l >> 4, r16 = l & 15;
  const int lin = (blockIdx.x & 7) * 128 + (blockIdx.x >> 3);
  const int bh = lin >> 5;                         // b*NH + h (4 per XCD)
  const int q0 = (lin & 31) * 64 + w * 16;
  const short* Qb = Qp + (size_t)bh * S_LEN * DK;
  const short* Kb = Kp + (size_t)bh * S_LEN * DK;
  const short* Vb = Vp + (size_t)bh * S_LEN * DK;

  const short8 qf0 = *(const short8*)(Qb + (size_t)(q0 + r16) * DK + g * 8);
  const short8 qf1 = *(const short8*)(Qb + (size_t)(q0 + r16) * DK + 32 + g * 8);

  float4v oacc[4];
#pragma unroll
  for (int j = 0; j < 4; ++j) oacc[j] = (float4v){0.f, 0.f, 0.f, 0.f};
  float m_run = -3.0e38f, l_run = 0.f;

  // V loader: coalesced loads (8 lanes cover a 128B row chunk), swizzled write
  const int va  = tid >> 3;                 // kv pair 0..31
  const int vdb = (tid & 7) * 8;            // d base
  const int vcs = va ^ ((tid & 7) << 2);    // swizzled column (2-way banks)

  // --- prefetch tile 0 into registers ---
  short8 vr0 = *(const short8*)(Vb + (size_t)(2 * va) * DK + vdb);
  short8 vr1 = *(const short8*)(Vb + (size_t)(2 * va + 1) * DK + vdb);
  short8 kr0[4], kr1[4];
#pragma unroll
  for (int s = 0; s < 4; ++s) {
    kr0[s] = *(const short8*)(Kb + (size_t)(s * 16 + r16) * DK + g * 8);
    kr1[s] = *(const short8*)(Kb + (size_t)(s * 16 + r16) * DK + 32 + g * 8);
  }

  for (int t = 0; t < S_LEN / 64; ++t) {
    const int buf = t & 1;
    // --- stage V tile t from regs into Vtu[buf] (swizzled, 2-way banks) ---
#pragma unroll
    for (int i = 0; i < 8; ++i) {
      const unsigned pk = ((unsigned)(unsigned short)vr0[i]) |
                          (((unsigned)(unsigned short)vr1[i]) << 16);
      Vtu[buf][vdb + i][vcs] = pk;
    }

    // --- QK^T with prefetched K (register-only) ---
    float4v st[4];
#pragma unroll
    for (int s = 0; s < 4; ++s) {
      float4v a = (float4v){0.f, 0.f, 0.f, 0.f};
      a = __builtin_amdgcn_mfma_f32_16x16x32_bf16(kr0[s], qf0, a, 0, 0, 0);
      a = __builtin_amdgcn_mfma_f32_16x16x32_bf16(kr1[s], qf1, a, 0, 0, 0);
      st[s] = a;
    }

    // --- prefetch V,K for tile t+1 (wraps to 0 on last iter; harmless) ---
    const int nkv = ((t + 1) * 64) & (S_LEN - 1);
    vr0 = *(const short8*)(Vb + (size_t)(nkv + 2 * va) * DK + vdb);
    vr1 = *(const short8*)(Vb + (size_t)(nkv + 2 * va + 1) * DK + vdb);
#pragma unroll
    for (int s = 0; s < 4; ++s) {
      kr0[s] = *(const short8*)(Kb + (size_t)(nkv + s * 16 + r16) * DK + g * 8);
      kr1[s] = *(const short8*)(Kb + (size_t)(nkv + s * 16 + r16) * DK + 32 + g * 8);
    }

    // --- online softmax (register-only; q = l&15, 16 kv values) ---
    float mt = -3.0e38f;
#pragma unroll
    for (int s = 0; s < 4; ++s)
#pragma unroll
      for (int r = 0; r < 4; ++r) mt = fmaxf(mt, st[s][r]);
    mt = fmaxf(mt, __shfl_xor(mt, 16));
    mt = fmaxf(mt, __shfl_xor(mt, 32));
    const float m_new = fmaxf(m_run, mt);
    const float alpha = __expf(m_run - m_new);
    float psum = 0.f;
#pragma unroll
    for (int s = 0; s < 4; ++s)
#pragma unroll
      for (int r = 0; r < 4; ++r) {
        const float p = __expf(st[s][r] - m_new);
        st[s][r] = p;
        psum += p;
      }
    l_run = l_run * alpha + psum;
    m_run = m_new;

    // --- rescale O by alpha ---
    const float ar0 = __shfl(alpha, g * 4 + 0);
    const float ar1 = __shfl(alpha, g * 4 + 1);
    const float ar2 = __shfl(alpha, g * 4 + 2);
    const float ar3 = __shfl(alpha, g * 4 + 3);
#pragma unroll
    for (int j = 0; j < 4; ++j) {
      oacc[j][0] *= ar0; oacc[j][1] *= ar1;
      oacc[j][2] *= ar2; oacc[j][3] *= ar3;
    }

    // --- single barrier: Vtu[buf] writes visible; separates buf reuse ---
    __syncthreads();

    // --- P -> per-wave LDS (same-wave RAW, no barrier needed) ---
#pragma unroll
    for (int s = 0; s < 4; ++s) {
      Plu[w][r16][s * 8 + g * 2]     = cvt2(st[s][0], st[s][1]);
      Plu[w][r16][s * 8 + g * 2 + 1] = cvt2(st[s][2], st[s][3]);
    }

    // --- PV: O += P(16x64) * V(64x64), swizzled V reads ---
#pragma unroll
    for (int kc = 0; kc < 2; ++kc) {
      const short8 pf = __builtin_bit_cast(short8, *(const uint4v*)&Plu[w][r16][kc * 16 + g * 4]);
#pragma unroll
      for (int j = 0; j < 4; ++j) {
        const int h = (2 * j + (r16 >> 3)) & 7;
        const short8 vf = __builtin_bit_cast(short8,
            *(const uint4v*)&Vtu[buf][j * 16 + r16][4 * (((kc << 2) + g) ^ h)]);
        oacc[j] = __builtin_amdgcn_mfma_f32_16x16x32_bf16(pf, vf, oacc[j], 0, 0, 0);
      }
    }
  }

  // --- finalize ---
  float lt = l_run + __shfl_xor(l_run, 16);
  lt = lt + __shfl_xor(lt, 32);
  const float li0 = 1.f / __shfl(lt, g * 4 + 0);
  const float li1 = 1.f / __shfl(lt, g * 4 + 1);
  const float li2 = 1.f / __shfl(lt, g * 4 + 2);
  const float li3 = 1.f / __shfl(lt, g * 4 + 3);
  const int b = bh >> 4, h = bh & 15;
#pragma unroll
  for (int j = 0; j < 4; ++j) {
    const int d = h * DK + j * 16 + r16;
    const int qr = q0 + g * 4;
    ctx[(size_t)(b * S_LEN + qr + 0) * EMB + d] = f2b(oacc[j][0] * li0);
    ctx[(size_t)(b * S_LEN + qr + 1) * EMB + d] = f2b(oacc[j][1] * li1);
    ctx[(size_t)(b * S_LEN + qr + 2) * EMB + d] = f2b(oacc[j][2] * li2);
    ctx[(size_t)(b * S_LEN + qr + 3) * EMB + d] = f2b(oacc[j][3] * li3);
  }
}

// ---------------------------------------------------------------------------
extern "C" void kernel_launch(void* const* d_in, const int* in_sizes, int n_in,
                              void* d_out, int out_size, void* d_ws, size_t ws_size,
                              hipStream_t stream)
{
  const float* q  = (const float*)d_in[0];
  const float* k  = (const float*)d_in[1];
  const float* v  = (const float*)d_in[2];
  const float* Wq = (const float*)d_in[3];
  const float* bq = (const float*)d_in[4];
  const float* Wk = (const float*)d_in[5];
  const float* bk = (const float*)d_in[6];
  const float* Wv = (const float*)d_in[7];
  const float* bv = (const float*)d_in[8];
  const float* Wo = (const float*)d_in[9];
  const float* bo = (const float*)d_in[10];

  short* ws = (short*)d_ws;
  const size_t WSZ  = (size_t)EMB * EMB;   // 1M elems per weight matrix
  const size_t PROJ = (size_t)MTOT * EMB;  // 4M elems per activation
  short* Wqb = ws;                 // bf16 weights: 4 x 2 MB
  short* Wkb = ws + WSZ;
  short* Wvb = ws + 2 * WSZ;
  short* Wob = ws + 3 * WSZ;
  short* Qp  = ws + 4 * WSZ;       // (B,H,S,DK) bf16, pre-scaled by 1/8
  short* Vp  = Qp + PROJ;
  short* Cx  = Vp + PROJ;          // (B*S, E) bf16 context
  short* Kp  = (short*)d_out;      // K parks in d_out; consumed before final GEMM

  const int n4 = (int)(WSZ / 4);
  dim3 cg((n4 + 255) / 256), cb(256);
  cvt_f32_bf16<<<cg, cb, 0, stream>>>(Wq, Wqb, n4);
  cvt_f32_bf16<<<cg, cb, 0, stream>>>(Wk, Wkb, n4);
  cvt_f32_bf16<<<cg, cb, 0, stream>>>(Wv, Wvb, n4);
  cvt_f32_bf16<<<cg, cb, 0, stream>>>(Wo, Wob, n4);

  dim3 gb(256), tb(256);  // 1D, XCD-swizzled in-kernel
  gemm_nt<0><<<gb, tb, 0, stream>>>(q, Wqb, bq, Qp, 0.125f);  // scale folded
  gemm_nt<0><<<gb, tb, 0, stream>>>(k, Wkb, bk, Kp, 1.0f);
  gemm_nt<0><<<gb, tb, 0, stream>>>(v, Wvb, bv, Vp, 1.0f);
  attn_kernel<<<dim3(1024), tb, 0, stream>>>(Qp, Kp, Vp, Cx);
  gemm_nt<1><<<gb, tb, 0, stream>>>(Cx, Wob, bo, d_out, 1.0f);
}

// Round 7
// 256.672 us; speedup vs baseline: 1.1443x; 1.0720x over previous
//
#include <hip/hip_runtime.h>
#include <stdint.h>

// Problem constants
#define S_LEN 2048
#define EMB   1024
#define NH    16
#define DK    64
#define BATCH 2
#define MTOT  (BATCH * S_LEN)  // 4096

typedef __attribute__((ext_vector_type(8))) short    short8;
typedef __attribute__((ext_vector_type(4))) float    f32x4;
typedef __attribute__((ext_vector_type(4))) float    float4v;
typedef __attribute__((ext_vector_type(4))) unsigned uint4v;
typedef __attribute__((ext_vector_type(2))) unsigned uint2v;

__device__ __forceinline__ short f2b(float f) {
  unsigned u = __builtin_bit_cast(unsigned, f);
  u = (u + 0x7FFFu + ((u >> 16) & 1u)) >> 16;  // RNE to bf16
  return (short)u;
}
// pack two f32 -> two bf16 in one uint (low = a, high = b)
__device__ __forceinline__ unsigned cvt2(float a, float b) {
  unsigned r;
  asm("v_cvt_pk_bf16_f32 %0, %1, %2" : "=v"(r) : "v"(a), "v"(b));
  return r;
}

// ---------------------------------------------------------------------------
// Fused f32 -> bf16 weight convert: grid (WSZ/4/256, 4), y picks the matrix.
// ---------------------------------------------------------------------------
__global__ __launch_bounds__(256) void cvt_w4(const float* __restrict__ w0,
                                              const float* __restrict__ w1,
                                              const float* __restrict__ w2,
                                              const float* __restrict__ w3,
                                              short* __restrict__ dst)
{
  const size_t WSZ = (size_t)EMB * EMB;
  const int y = blockIdx.y;
  const float* src = (y == 0) ? w0 : (y == 1) ? w1 : (y == 2) ? w2 : w3;
  short* d = dst + (size_t)y * WSZ;
  const int i = blockIdx.x * 256 + threadIdx.x;  // exact cover, no tail
  const f32x4 v = *(const f32x4*)(src + (size_t)i * 4);
  uint2v p;
  p[0] = cvt2(v[0], v[1]);
  p[1] = cvt2(v[2], v[3]);
  *(uint2v*)(d + (size_t)i * 4) = p;
}

// ---------------------------------------------------------------------------
// Shared NT-GEMM body: C(128x128 tile) = A(M x K) * W(N x K)^T + bias.
// BK=64, 256 threads (4 waves 2x2, wave tile 64x64 = 4x4 MFMA frags).
// LDS k-chunk-major [chunk8][row128][16B]: fragment read = one ds_read_b128.
// MODE 0: A = f32 (cvt to bf16 in staging); out = bf16 scattered (B,H,S,DK).
// MODE 1: A = bf16; out = f32 row-major (M,N).
// ---------------------------------------------------------------------------
template <int MODE>
__device__ __forceinline__ void gemm_body(const float* __restrict__ Af0,
                                          const short* __restrict__ Ab0,
                                          const short* __restrict__ W,
                                          const float* __restrict__ bias,
                                          short* __restrict__ outb,
                                          float* __restrict__ outf,
                                          float scale, int m0, int n0)
{
  __shared__ __align__(16) unsigned Au[8][128][4];  // 16 KB
  __shared__ __align__(16) unsigned Bu[8][128][4];  // 16 KB
  const int tid = threadIdx.x;
  const int w = tid >> 6, l = tid & 63;
  const int g = l >> 4, r16 = l & 15;
  const int wr = w >> 1, wc = w & 1;
  const int srow = tid >> 3, shc = tid & 7;

  float4v acc[4][4];
#pragma unroll
  for (int i = 0; i < 4; ++i)
#pragma unroll
    for (int j = 0; j < 4; ++j)
      acc[i][j] = (float4v){0.f, 0.f, 0.f, 0.f};

  const float* Af = Af0 + (size_t)m0 * EMB;
  const short* Ab = Ab0 + (size_t)m0 * EMB;
  const short* Wbase = W + (size_t)n0 * EMB;

  for (int k0 = 0; k0 < EMB; k0 += 64) {
    uint4v apk[4], bpk[4];
    if constexpr (MODE == 0) {
#pragma unroll
      for (int p = 0; p < 4; ++p) {
        const float* src = Af + (size_t)(p * 32 + srow) * EMB + k0 + shc * 8;
        const f32x4 x = *(const f32x4*)src;
        const f32x4 y = *(const f32x4*)(src + 4);
        apk[p][0] = cvt2(x[0], x[1]);
        apk[p][1] = cvt2(x[2], x[3]);
        apk[p][2] = cvt2(y[0], y[1]);
        apk[p][3] = cvt2(y[2], y[3]);
      }
    } else {
#pragma unroll
      for (int p = 0; p < 4; ++p)
        apk[p] = __builtin_bit_cast(uint4v,
            *(const short8*)(Ab + (size_t)(p * 32 + srow) * EMB + k0 + shc * 8));
    }
#pragma unroll
    for (int p = 0; p < 4; ++p)
      bpk[p] = __builtin_bit_cast(uint4v,
          *(const short8*)(Wbase + (size_t)(p * 32 + srow) * EMB + k0 + shc * 8));

    __syncthreads();
#pragma unroll
    for (int p = 0; p < 4; ++p)
      *(uint4v*)&Au[shc][p * 32 + srow][0] = apk[p];
#pragma unroll
    for (int p = 0; p < 4; ++p)
      *(uint4v*)&Bu[shc][p * 32 + srow][0] = bpk[p];
    __syncthreads();

#pragma unroll
    for (int ks = 0; ks < 2; ++ks) {
      const int c = ks * 4 + g;
      short8 af[4], bf[4];
#pragma unroll
      for (int i = 0; i < 4; ++i)
        af[i] = __builtin_bit_cast(short8, *(const uint4v*)&Au[c][wr * 64 + i * 16 + r16][0]);
#pragma unroll
      for (int j = 0; j < 4; ++j)
        bf[j] = __builtin_bit_cast(short8, *(const uint4v*)&Bu[c][wc * 64 + j * 16 + r16][0]);
#pragma unroll
      for (int i = 0; i < 4; ++i)
#pragma unroll
        for (int j = 0; j < 4; ++j)
          acc[i][j] = __builtin_amdgcn_mfma_f32_16x16x32_bf16(af[i], bf[j], acc[i][j], 0, 0, 0);
    }
  }

  // Epilogue: C/D layout col = l&15, row = (l>>4)*4 + r
#pragma unroll
  for (int j = 0; j < 4; ++j) {
    const int n = n0 + wc * 64 + j * 16 + r16;
    const float bv = bias[n];
#pragma unroll
    for (int i = 0; i < 4; ++i) {
#pragma unroll
      for (int r = 0; r < 4; ++r) {
        const int m = m0 + wr * 64 + i * 16 + g * 4 + r;
        const float vv = (acc[i][j][r] + bv) * scale;
        if constexpr (MODE == 0) {
          const int b = m >> 11, s = m & (S_LEN - 1);
          const int h = n >> 6, d = n & (DK - 1);
          outb[(size_t)((b * NH + h) * S_LEN + s) * DK + d] = f2b(vv);
        } else {
          outf[(size_t)m * EMB + n] = vv;
        }
      }
    }
  }
}

// Fused Q/K/V projections: grid 768 blocks (3 per CU co-resident).
// Q output is pre-scaled by (1/sqrt(dk)) * log2(e) for exp2-domain softmax.
__global__ __launch_bounds__(256) void gemm_qkv(const float* __restrict__ q,
                                                const float* __restrict__ k,
                                                const float* __restrict__ v,
                                                const short* __restrict__ Wb,
                                                const float* __restrict__ bq,
                                                const float* __restrict__ bk,
                                                const float* __restrict__ bv,
                                                short* __restrict__ Qp,
                                                short* __restrict__ Kp,
                                                short* __restrict__ Vp)
{
  const int which = blockIdx.x >> 8;
  const int inner = blockIdx.x & 255;
  const int lin = (inner & 7) * 32 + (inner >> 3);  // XCD swizzle
  const int m0 = (lin >> 3) * 128, n0 = (lin & 7) * 128;
  const float* A    = (which == 0) ? q  : (which == 1) ? k  : v;
  const float* bias = (which == 0) ? bq : (which == 1) ? bk : bv;
  short* out        = (which == 0) ? Qp : (which == 1) ? Kp : Vp;
  const short* W = Wb + (size_t)which * EMB * EMB;
  const float scale = (which == 0) ? 0.125f * 1.44269504088896f : 1.0f;
  gemm_body<0>(A, nullptr, W, bias, out, nullptr, scale, m0, n0);
}

__global__ __launch_bounds__(256) void gemm_out(const short* __restrict__ Cx,
                                                const short* __restrict__ Wob,
                                                const float* __restrict__ bo,
                                                float* __restrict__ outp)
{
  const int lin = (blockIdx.x & 7) * 32 + (blockIdx.x >> 3);
  gemm_body<1>(nullptr, Cx, Wob, bo, nullptr, outp, 1.0f, (lin >> 3) * 128, (lin & 7) * 128);
}

// ---------------------------------------------------------------------------
// Flash attention (exp2-domain softmax; scores pre-scaled by 0.125*log2e in
// the Q projection). Grid 1024 XCD-swizzled. Block 256 = 4 waves x 16 q.
//  - K/V register-prefetch one tile ahead; double-buffered V^T in LDS,
//    ONE barrier/iter
//  - P re-fragmentation for PV done entirely with wave shuffles (no P LDS):
//    target lane (g,q) pulls packed bf16 pairs from lanes 32(g&1)+q, +16,
//    slot 2kc+(g>>1)
//  - setprio(1) around MFMA clusters (T5)
// ---------------------------------------------------------------------------
__global__ __launch_bounds__(256, 4) void attn_kernel(const short* __restrict__ Qp,
                                                      const short* __restrict__ Kp,
                                                      const short* __restrict__ Vp,
                                                      short* __restrict__ ctx)
{
  __shared__ __align__(16) unsigned Vtu[2][64][36];  // 18432 B
  const int tid = threadIdx.x;
  const int w = tid >> 6, l = tid & 63;
  const int g = l >> 4, r16 = l & 15;
  const int lin = (blockIdx.x & 7) * 128 + (blockIdx.x >> 3);
  const int bh = lin >> 5;                         // b*NH + h (4 per XCD)
  const int q0 = (lin & 31) * 64 + w * 16;
  const short* Qb = Qp + (size_t)bh * S_LEN * DK;
  const short* Kb = Kp + (size_t)bh * S_LEN * DK;
  const short* Vb = Vp + (size_t)bh * S_LEN * DK;

  const short8 qf0 = *(const short8*)(Qb + (size_t)(q0 + r16) * DK + g * 8);
  const short8 qf1 = *(const short8*)(Qb + (size_t)(q0 + r16) * DK + 32 + g * 8);

  float4v oacc[4];
#pragma unroll
  for (int j = 0; j < 4; ++j) oacc[j] = (float4v){0.f, 0.f, 0.f, 0.f};
  float m_run = -3.0e38f, l_run = 0.f;

  // V loader: coalesced loads, swizzled LDS write (2-way banks = free)
  const int va  = tid >> 3;                 // kv pair 0..31
  const int vdb = (tid & 7) * 8;            // d base
  const int vcs = va ^ ((tid & 7) << 2);    // swizzled column

  // shuffle sources for P re-fragmentation
  const int lA = ((l >> 4) & 1) * 32 + r16;
  const int lB = lA + 16;
  const bool gh = ((l >> 5) & 1) != 0;      // g>>1

  // --- prefetch tile 0 ---
  short8 vr0 = *(const short8*)(Vb + (size_t)(2 * va) * DK + vdb);
  short8 vr1 = *(const short8*)(Vb + (size_t)(2 * va + 1) * DK + vdb);
  short8 kr0[4], kr1[4];
#pragma unroll
  for (int s = 0; s < 4; ++s) {
    kr0[s] = *(const short8*)(Kb + (size_t)(s * 16 + r16) * DK + g * 8);
    kr1[s] = *(const short8*)(Kb + (size_t)(s * 16 + r16) * DK + 32 + g * 8);
  }

  for (int t = 0; t < S_LEN / 64; ++t) {
    const int buf = t & 1;
    // --- stage V tile t (swizzled) ---
#pragma unroll
    for (int i = 0; i < 8; ++i) {
      const unsigned pk = ((unsigned)(unsigned short)vr0[i]) |
                          (((unsigned)(unsigned short)vr1[i]) << 16);
      Vtu[buf][vdb + i][vcs] = pk;
    }

    // --- QK^T (register-only) ---
    float4v st[4];
    __builtin_amdgcn_s_setprio(1);
#pragma unroll
    for (int s = 0; s < 4; ++s) {
      float4v a = (float4v){0.f, 0.f, 0.f, 0.f};
      a = __builtin_amdgcn_mfma_f32_16x16x32_bf16(kr0[s], qf0, a, 0, 0, 0);
      a = __builtin_amdgcn_mfma_f32_16x16x32_bf16(kr1[s], qf1, a, 0, 0, 0);
      st[s] = a;
    }
    __builtin_amdgcn_s_setprio(0);

    // --- prefetch V,K for tile t+1 (wraps on last iter; harmless) ---
    const int nkv = ((t + 1) * 64) & (S_LEN - 1);
    vr0 = *(const short8*)(Vb + (size_t)(nkv + 2 * va) * DK + vdb);
    vr1 = *(const short8*)(Vb + (size_t)(nkv + 2 * va + 1) * DK + vdb);
#pragma unroll
    for (int s = 0; s < 4; ++s) {
      kr0[s] = *(const short8*)(Kb + (size_t)(nkv + s * 16 + r16) * DK + g * 8);
      kr1[s] = *(const short8*)(Kb + (size_t)(nkv + s * 16 + r16) * DK + 32 + g * 8);
    }

    // --- online softmax, exp2 domain, tree reductions ---
    float mx[4];
#pragma unroll
    for (int s = 0; s < 4; ++s)
      mx[s] = fmaxf(fmaxf(st[s][0], st[s][1]), fmaxf(st[s][2], st[s][3]));
    float mt = fmaxf(fmaxf(mx[0], mx[1]), fmaxf(mx[2], mx[3]));
    mt = fmaxf(mt, __shfl_xor(mt, 16));
    mt = fmaxf(mt, __shfl_xor(mt, 32));
    const float m_new = fmaxf(m_run, mt);
    const float alpha = exp2f(m_run - m_new);
    float ps[4];
#pragma unroll
    for (int s = 0; s < 4; ++s) {
      const float p0 = exp2f(st[s][0] - m_new);
      const float p1 = exp2f(st[s][1] - m_new);
      const float p2 = exp2f(st[s][2] - m_new);
      const float p3 = exp2f(st[s][3] - m_new);
      st[s][0] = p0; st[s][1] = p1; st[s][2] = p2; st[s][3] = p3;
      ps[s] = (p0 + p1) + (p2 + p3);
    }
    l_run = l_run * alpha + ((ps[0] + ps[1]) + (ps[2] + ps[3]));
    m_run = m_new;

    // --- pack P pairs (bf16) and redistribute via shuffles ---
    unsigned pp0[4], pp1[4];
#pragma unroll
    for (int s = 0; s < 4; ++s) {
      pp0[s] = cvt2(st[s][0], st[s][1]);
      pp1[s] = cvt2(st[s][2], st[s][3]);
    }
    uint4v pu0, pu1;
    {
      const unsigned a0 = __shfl(pp0[0], lA), b0 = __shfl(pp0[1], lA);
      const unsigned a1 = __shfl(pp1[0], lA), b1 = __shfl(pp1[1], lA);
      const unsigned a2 = __shfl(pp0[0], lB), b2 = __shfl(pp0[1], lB);
      const unsigned a3 = __shfl(pp1[0], lB), b3 = __shfl(pp1[1], lB);
      pu0[0] = gh ? b0 : a0; pu0[1] = gh ? b1 : a1;
      pu0[2] = gh ? b2 : a2; pu0[3] = gh ? b3 : a3;
    }
    {
      const unsigned a0 = __shfl(pp0[2], lA), b0 = __shfl(pp0[3], lA);
      const unsigned a1 = __shfl(pp1[2], lA), b1 = __shfl(pp1[3], lA);
      const unsigned a2 = __shfl(pp0[2], lB), b2 = __shfl(pp0[3], lB);
      const unsigned a3 = __shfl(pp1[2], lB), b3 = __shfl(pp1[3], lB);
      pu1[0] = gh ? b0 : a0; pu1[1] = gh ? b1 : a1;
      pu1[2] = gh ? b2 : a2; pu1[3] = gh ? b3 : a3;
    }
    const short8 pf0 = __builtin_bit_cast(short8, pu0);
    const short8 pf1 = __builtin_bit_cast(short8, pu1);

    // --- rescale O by alpha ---
    const float ar0 = __shfl(alpha, g * 4 + 0);
    const float ar1 = __shfl(alpha, g * 4 + 1);
    const float ar2 = __shfl(alpha, g * 4 + 2);
    const float ar3 = __shfl(alpha, g * 4 + 3);
#pragma unroll
    for (int j = 0; j < 4; ++j) {
      oacc[j][0] *= ar0; oacc[j][1] *= ar1;
      oacc[j][2] *= ar2; oacc[j][3] *= ar3;
    }

    // --- single barrier: Vtu[buf] writes visible ---
    __syncthreads();

    // --- PV: O += P(16x64) * V(64x64), swizzled V reads ---
    __builtin_amdgcn_s_setprio(1);
#pragma unroll
    for (int kc = 0; kc < 2; ++kc) {
      const short8 pf = kc ? pf1 : pf0;
#pragma unroll
      for (int j = 0; j < 4; ++j) {
        const int h = (2 * j + (r16 >> 3)) & 7;
        const short8 vf = __builtin_bit_cast(short8,
            *(const uint4v*)&Vtu[buf][j * 16 + r16][4 * (((kc << 2) + g) ^ h)]);
        oacc[j] = __builtin_amdgcn_mfma_f32_16x16x32_bf16(pf, vf, oacc[j], 0, 0, 0);
      }
    }
    __builtin_amdgcn_s_setprio(0);
  }

  // --- finalize ---
  float lt = l_run + __shfl_xor(l_run, 16);
  lt = lt + __shfl_xor(lt, 32);
  const float li0 = 1.f / __shfl(lt, g * 4 + 0);
  const float li1 = 1.f / __shfl(lt, g * 4 + 1);
  const float li2 = 1.f / __shfl(lt, g * 4 + 2);
  const float li3 = 1.f / __shfl(lt, g * 4 + 3);
  const int b = bh >> 4, h = bh & 15;
#pragma unroll
  for (int j = 0; j < 4; ++j) {
    const int d = h * DK + j * 16 + r16;
    const int qr = q0 + g * 4;
    ctx[(size_t)(b * S_LEN + qr + 0) * EMB + d] = f2b(oacc[j][0] * li0);
    ctx[(size_t)(b * S_LEN + qr + 1) * EMB + d] = f2b(oacc[j][1] * li1);
    ctx[(size_t)(b * S_LEN + qr + 2) * EMB + d] = f2b(oacc[j][2] * li2);
    ctx[(size_t)(b * S_LEN + qr + 3) * EMB + d] = f2b(oacc[j][3] * li3);
  }
}

// ---------------------------------------------------------------------------
extern "C" void kernel_launch(void* const* d_in, const int* in_sizes, int n_in,
                              void* d_out, int out_size, void* d_ws, size_t ws_size,
                              hipStream_t stream)
{
  const float* q  = (const float*)d_in[0];
  const float* k  = (const float*)d_in[1];
  const float* v  = (const float*)d_in[2];
  const float* Wq = (const float*)d_in[3];
  const float* bq = (const float*)d_in[4];
  const float* Wk = (const float*)d_in[5];
  const float* bk = (const float*)d_in[6];
  const float* Wv = (const float*)d_in[7];
  const float* bv = (const float*)d_in[8];
  const float* Wo = (const float*)d_in[9];
  const float* bo = (const float*)d_in[10];

  short* ws = (short*)d_ws;
  const size_t WSZ  = (size_t)EMB * EMB;   // 1M elems per weight matrix
  const size_t PROJ = (size_t)MTOT * EMB;  // 4M elems per activation
  short* Wb  = ws;                 // bf16 weights: Wq,Wk,Wv consecutive + Wo
  short* Wob = ws + 3 * WSZ;
  short* Qp  = ws + 4 * WSZ;       // (B,H,S,DK) bf16, pre-scaled
  short* Vp  = Qp + PROJ;
  short* Cx  = Vp + PROJ;          // (B*S, E) bf16 context
  short* Kp  = (short*)d_out;      // K parks in d_out; consumed before final GEMM

  cvt_w4<<<dim3((int)(WSZ / 4 / 256), 4), dim3(256), 0, stream>>>(Wq, Wk, Wv, Wo, ws);

  gemm_qkv<<<dim3(768), dim3(256), 0, stream>>>(q, k, v, Wb, bq, bk, bv, Qp, Kp, Vp);
  attn_kernel<<<dim3(1024), dim3(256), 0, stream>>>(Qp, Kp, Vp, Cx);
  gemm_out<<<dim3(256), dim3(256), 0, stream>>>(Cx, Wob, bo, (float*)d_out);
}

// Round 8
// 224.883 us; speedup vs baseline: 1.3061x; 1.1414x over previous
//
#include <hip/hip_runtime.h>
#include <stdint.h>

// Problem constants
#define S_LEN 2048
#define EMB   1024
#define NH    16
#define DK    64
#define BATCH 2
#define MTOT  (BATCH * S_LEN)  // 4096

typedef __attribute__((ext_vector_type(8))) short    short8;
typedef __attribute__((ext_vector_type(4))) float    f32x4;
typedef __attribute__((ext_vector_type(4))) float    float4v;
typedef __attribute__((ext_vector_type(4))) unsigned uint4v;
typedef __attribute__((ext_vector_type(2))) unsigned uint2v;

__device__ __forceinline__ short f2b(float f) {
  unsigned u = __builtin_bit_cast(unsigned, f);
  u = (u + 0x7FFFu + ((u >> 16) & 1u)) >> 16;  // RNE to bf16
  return (short)u;
}
// pack two f32 -> two bf16 in one uint (low = a, high = b)
__device__ __forceinline__ unsigned cvt2(float a, float b) {
  unsigned r;
  asm("v_cvt_pk_bf16_f32 %0, %1, %2" : "=v"(r) : "v"(a), "v"(b));
  return r;
}

// ---------------------------------------------------------------------------
// Fused f32 -> bf16 weight convert: grid (WSZ/4/256, 4), y picks the matrix.
// ---------------------------------------------------------------------------
__global__ __launch_bounds__(256) void cvt_w4(const float* __restrict__ w0,
                                              const float* __restrict__ w1,
                                              const float* __restrict__ w2,
                                              const float* __restrict__ w3,
                                              short* __restrict__ dst)
{
  const size_t WSZ = (size_t)EMB * EMB;
  const int y = blockIdx.y;
  const float* src = (y == 0) ? w0 : (y == 1) ? w1 : (y == 2) ? w2 : w3;
  short* d = dst + (size_t)y * WSZ;
  const int i = blockIdx.x * 256 + threadIdx.x;  // exact cover, no tail
  const f32x4 v = *(const f32x4*)(src + (size_t)i * 4);
  uint2v p;
  p[0] = cvt2(v[0], v[1]);
  p[1] = cvt2(v[2], v[3]);
  *(uint2v*)(d + (size_t)i * 4) = p;
}

// ---------------------------------------------------------------------------
// Shared NT-GEMM body, software-pipelined staging:
//   prologue: load tile 0 into regs
//   loop:     barrier; regs -> LDS; barrier; issue loads for tile k+1;
//             16 MFMAs on LDS tile k  (loads land under the MFMA block)
// Tile 128x128, BK=64, 256 threads (4 waves 2x2, wave 64x64 = 4x4 frags).
// LDS k-chunk-major [chunk8][row128][16B]: fragment read = one ds_read_b128.
// MODE 0: A = f32 (cvt to bf16 at LDS-write); out = bf16 scattered (B,H,S,DK).
// MODE 1: A = bf16; out = f32 row-major (M,N).
// ---------------------------------------------------------------------------
template <int MODE>
__device__ __forceinline__ void gemm_body(const float* __restrict__ Af0,
                                          const short* __restrict__ Ab0,
                                          const short* __restrict__ W,
                                          const float* __restrict__ bias,
                                          short* __restrict__ outb,
                                          float* __restrict__ outf,
                                          float scale, int m0, int n0)
{
  __shared__ __align__(16) unsigned Au[8][128][4];  // 16 KB
  __shared__ __align__(16) unsigned Bu[8][128][4];  // 16 KB
  const int tid = threadIdx.x;
  const int w = tid >> 6, l = tid & 63;
  const int g = l >> 4, r16 = l & 15;
  const int wr = w >> 1, wc = w & 1;
  const int srow = tid >> 3, shc = tid & 7;

  float4v acc[4][4];
#pragma unroll
  for (int i = 0; i < 4; ++i)
#pragma unroll
    for (int j = 0; j < 4; ++j)
      acc[i][j] = (float4v){0.f, 0.f, 0.f, 0.f};

  const float* Af = Af0 + (size_t)m0 * EMB;
  const short* Ab = Ab0 + (size_t)m0 * EMB;
  const short* Wbase = W + (size_t)n0 * EMB;

  f32x4  ax[4][2];   // MODE 0 raw A staging regs
  uint4v apk[4];     // MODE 1 A staging regs
  uint4v bpk[4];     // W staging regs

  // --- prologue: load tile k0 = 0 ---
#pragma unroll
  for (int p = 0; p < 4; ++p) {
    if constexpr (MODE == 0) {
      const float* src = Af + (size_t)(p * 32 + srow) * EMB + shc * 8;
      ax[p][0] = *(const f32x4*)src;
      ax[p][1] = *(const f32x4*)(src + 4);
    } else {
      apk[p] = __builtin_bit_cast(uint4v,
          *(const short8*)(Ab + (size_t)(p * 32 + srow) * EMB + shc * 8));
    }
    bpk[p] = __builtin_bit_cast(uint4v,
        *(const short8*)(Wbase + (size_t)(p * 32 + srow) * EMB + shc * 8));
  }

  for (int k0 = 0; k0 < EMB; k0 += 64) {
    // materialize write values (cvt for MODE 0)
    uint4v awr[4], bwr[4];
#pragma unroll
    for (int p = 0; p < 4; ++p) {
      if constexpr (MODE == 0) {
        awr[p][0] = cvt2(ax[p][0][0], ax[p][0][1]);
        awr[p][1] = cvt2(ax[p][0][2], ax[p][0][3]);
        awr[p][2] = cvt2(ax[p][1][0], ax[p][1][1]);
        awr[p][3] = cvt2(ax[p][1][2], ax[p][1][3]);
      } else {
        awr[p] = apk[p];
      }
      bwr[p] = bpk[p];
    }

    __syncthreads();   // previous tile's MFMAs done with LDS
#pragma unroll
    for (int p = 0; p < 4; ++p)
      *(uint4v*)&Au[shc][p * 32 + srow][0] = awr[p];
#pragma unroll
    for (int p = 0; p < 4; ++p)
      *(uint4v*)&Bu[shc][p * 32 + srow][0] = bwr[p];
    __syncthreads();   // tile k0 visible

    // issue next tile's loads; they complete under the MFMA block below
    if (k0 + 64 < EMB) {
      const int kn = k0 + 64;
#pragma unroll
      for (int p = 0; p < 4; ++p) {
        if constexpr (MODE == 0) {
          const float* src = Af + (size_t)(p * 32 + srow) * EMB + kn + shc * 8;
          ax[p][0] = *(const f32x4*)src;
          ax[p][1] = *(const f32x4*)(src + 4);
        } else {
          apk[p] = __builtin_bit_cast(uint4v,
              *(const short8*)(Ab + (size_t)(p * 32 + srow) * EMB + kn + shc * 8));
        }
        bpk[p] = __builtin_bit_cast(uint4v,
            *(const short8*)(Wbase + (size_t)(p * 32 + srow) * EMB + kn + shc * 8));
      }
    }

    __builtin_amdgcn_s_setprio(1);
#pragma unroll
    for (int ks = 0; ks < 2; ++ks) {
      const int c = ks * 4 + g;
      short8 af[4], bf[4];
#pragma unroll
      for (int i = 0; i < 4; ++i)
        af[i] = __builtin_bit_cast(short8, *(const uint4v*)&Au[c][wr * 64 + i * 16 + r16][0]);
#pragma unroll
      for (int j = 0; j < 4; ++j)
        bf[j] = __builtin_bit_cast(short8, *(const uint4v*)&Bu[c][wc * 64 + j * 16 + r16][0]);
#pragma unroll
      for (int i = 0; i < 4; ++i)
#pragma unroll
        for (int j = 0; j < 4; ++j)
          acc[i][j] = __builtin_amdgcn_mfma_f32_16x16x32_bf16(af[i], bf[j], acc[i][j], 0, 0, 0);
    }
    __builtin_amdgcn_s_setprio(0);
  }

  // Epilogue: C/D layout col = l&15, row = (l>>4)*4 + r
#pragma unroll
  for (int j = 0; j < 4; ++j) {
    const int n = n0 + wc * 64 + j * 16 + r16;
    const float bv = bias[n];
#pragma unroll
    for (int i = 0; i < 4; ++i) {
#pragma unroll
      for (int r = 0; r < 4; ++r) {
        const int m = m0 + wr * 64 + i * 16 + g * 4 + r;
        const float vv = (acc[i][j][r] + bv) * scale;
        if constexpr (MODE == 0) {
          const int b = m >> 11, s = m & (S_LEN - 1);
          const int h = n >> 6, d = n & (DK - 1);
          outb[(size_t)((b * NH + h) * S_LEN + s) * DK + d] = f2b(vv);
        } else {
          outf[(size_t)m * EMB + n] = vv;
        }
      }
    }
  }
}

// Fused Q/K/V projections: grid 768 blocks.
// Q output pre-scaled by (1/sqrt(dk)) * log2(e) for exp2-domain softmax.
__global__ __launch_bounds__(256, 2) void gemm_qkv(const float* __restrict__ q,
                                                   const float* __restrict__ k,
                                                   const float* __restrict__ v,
                                                   const short* __restrict__ Wb,
                                                   const float* __restrict__ bq,
                                                   const float* __restrict__ bk,
                                                   const float* __restrict__ bv,
                                                   short* __restrict__ Qp,
                                                   short* __restrict__ Kp,
                                                   short* __restrict__ Vp)
{
  const int which = blockIdx.x >> 8;
  const int inner = blockIdx.x & 255;
  const int lin = (inner & 7) * 32 + (inner >> 3);  // XCD swizzle
  const int m0 = (lin >> 3) * 128, n0 = (lin & 7) * 128;
  const float* A    = (which == 0) ? q  : (which == 1) ? k  : v;
  const float* bias = (which == 0) ? bq : (which == 1) ? bk : bv;
  short* out        = (which == 0) ? Qp : (which == 1) ? Kp : Vp;
  const short* W = Wb + (size_t)which * EMB * EMB;
  const float scale = (which == 0) ? 0.125f * 1.44269504088896f : 1.0f;
  gemm_body<0>(A, nullptr, W, bias, out, nullptr, scale, m0, n0);
}

__global__ __launch_bounds__(256, 2) void gemm_out(const short* __restrict__ Cx,
                                                   const short* __restrict__ Wob,
                                                   const float* __restrict__ bo,
                                                   float* __restrict__ outp)
{
  const int lin = (blockIdx.x & 7) * 32 + (blockIdx.x >> 3);
  gemm_body<1>(nullptr, Cx, Wob, bo, nullptr, outp, 1.0f, (lin >> 3) * 128, (lin & 7) * 128);
}

// ---------------------------------------------------------------------------
// Flash attention (exp2-domain softmax; scores pre-scaled by 0.125*log2e in
// the Q projection). Grid 1024 XCD-swizzled. Block 256 = 4 waves x 16 q.
//  - K/V register-prefetch one tile ahead; double-buffered V^T in LDS,
//    ONE barrier/iter
//  - P goes through per-wave LDS strip (Plu): cheaper on the LDS pipe than
//    the shuffle redistribution (measured r6 vs r7)
//  - setprio(1) around MFMA clusters
// ---------------------------------------------------------------------------
__global__ __launch_bounds__(256, 4) void attn_kernel(const short* __restrict__ Qp,
                                                      const short* __restrict__ Kp,
                                                      const short* __restrict__ Vp,
                                                      short* __restrict__ ctx)
{
  __shared__ __align__(16) unsigned Vtu[2][64][36];  // 18432 B
  __shared__ __align__(16) unsigned Plu[4][16][36];  //  9216 B
  const int tid = threadIdx.x;
  const int w = tid >> 6, l = tid & 63;
  const int g = l >> 4, r16 = l & 15;
  const int lin = (blockIdx.x & 7) * 128 + (blockIdx.x >> 3);
  const int bh = lin >> 5;                         // b*NH + h (4 per XCD)
  const int q0 = (lin & 31) * 64 + w * 16;
  const short* Qb = Qp + (size_t)bh * S_LEN * DK;
  const short* Kb = Kp + (size_t)bh * S_LEN * DK;
  const short* Vb = Vp + (size_t)bh * S_LEN * DK;

  const short8 qf0 = *(const short8*)(Qb + (size_t)(q0 + r16) * DK + g * 8);
  const short8 qf1 = *(const short8*)(Qb + (size_t)(q0 + r16) * DK + 32 + g * 8);

  float4v oacc[4];
#pragma unroll
  for (int j = 0; j < 4; ++j) oacc[j] = (float4v){0.f, 0.f, 0.f, 0.f};
  float m_run = -3.0e38f, l_run = 0.f;

  // V loader: coalesced loads, swizzled LDS write (2-way banks = free)
  const int va  = tid >> 3;                 // kv pair 0..31
  const int vdb = (tid & 7) * 8;            // d base
  const int vcs = va ^ ((tid & 7) << 2);    // swizzled column

  // --- prefetch tile 0 ---
  short8 vr0 = *(const short8*)(Vb + (size_t)(2 * va) * DK + vdb);
  short8 vr1 = *(const short8*)(Vb + (size_t)(2 * va + 1) * DK + vdb);
  short8 kr0[4], kr1[4];
#pragma unroll
  for (int s = 0; s < 4; ++s) {
    kr0[s] = *(const short8*)(Kb + (size_t)(s * 16 + r16) * DK + g * 8);
    kr1[s] = *(const short8*)(Kb + (size_t)(s * 16 + r16) * DK + 32 + g * 8);
  }

  for (int t = 0; t < S_LEN / 64; ++t) {
    const int buf = t & 1;
    // --- stage V tile t (swizzled) ---
#pragma unroll
    for (int i = 0; i < 8; ++i) {
      const unsigned pk = ((unsigned)(unsigned short)vr0[i]) |
                          (((unsigned)(unsigned short)vr1[i]) << 16);
      Vtu[buf][vdb + i][vcs] = pk;
    }

    // --- QK^T (register-only) ---
    float4v st[4];
    __builtin_amdgcn_s_setprio(1);
#pragma unroll
    for (int s = 0; s < 4; ++s) {
      float4v a = (float4v){0.f, 0.f, 0.f, 0.f};
      a = __builtin_amdgcn_mfma_f32_16x16x32_bf16(kr0[s], qf0, a, 0, 0, 0);
      a = __builtin_amdgcn_mfma_f32_16x16x32_bf16(kr1[s], qf1, a, 0, 0, 0);
      st[s] = a;
    }
    __builtin_amdgcn_s_setprio(0);

    // --- prefetch V,K for tile t+1 (wraps on last iter; harmless) ---
    const int nkv = ((t + 1) * 64) & (S_LEN - 1);
    vr0 = *(const short8*)(Vb + (size_t)(nkv + 2 * va) * DK + vdb);
    vr1 = *(const short8*)(Vb + (size_t)(nkv + 2 * va + 1) * DK + vdb);
#pragma unroll
    for (int s = 0; s < 4; ++s) {
      kr0[s] = *(const short8*)(Kb + (size_t)(nkv + s * 16 + r16) * DK + g * 8);
      kr1[s] = *(const short8*)(Kb + (size_t)(nkv + s * 16 + r16) * DK + 32 + g * 8);
    }

    // --- online softmax, exp2 domain, tree reductions ---
    float mx[4];
#pragma unroll
    for (int s = 0; s < 4; ++s)
      mx[s] = fmaxf(fmaxf(st[s][0], st[s][1]), fmaxf(st[s][2], st[s][3]));
    float mt = fmaxf(fmaxf(mx[0], mx[1]), fmaxf(mx[2], mx[3]));
    mt = fmaxf(mt, __shfl_xor(mt, 16));
    mt = fmaxf(mt, __shfl_xor(mt, 32));
    const float m_new = fmaxf(m_run, mt);
    const float alpha = exp2f(m_run - m_new);
    float ps[4];
#pragma unroll
    for (int s = 0; s < 4; ++s) {
      const float p0 = exp2f(st[s][0] - m_new);
      const float p1 = exp2f(st[s][1] - m_new);
      const float p2 = exp2f(st[s][2] - m_new);
      const float p3 = exp2f(st[s][3] - m_new);
      st[s][0] = p0; st[s][1] = p1; st[s][2] = p2; st[s][3] = p3;
      ps[s] = (p0 + p1) + (p2 + p3);
    }
    l_run = l_run * alpha + ((ps[0] + ps[1]) + (ps[2] + ps[3]));
    m_run = m_new;

    // --- P -> per-wave LDS (bf16 pairs; same-wave RAW, no barrier) ---
#pragma unroll
    for (int s = 0; s < 4; ++s) {
      Plu[w][r16][s * 8 + g * 2]     = cvt2(st[s][0], st[s][1]);
      Plu[w][r16][s * 8 + g * 2 + 1] = cvt2(st[s][2], st[s][3]);
    }

    // --- rescale O by alpha ---
    const float ar0 = __shfl(alpha, g * 4 + 0);
    const float ar1 = __shfl(alpha, g * 4 + 1);
    const float ar2 = __shfl(alpha, g * 4 + 2);
    const float ar3 = __shfl(alpha, g * 4 + 3);
#pragma unroll
    for (int j = 0; j < 4; ++j) {
      oacc[j][0] *= ar0; oacc[j][1] *= ar1;
      oacc[j][2] *= ar2; oacc[j][3] *= ar3;
    }

    // --- single barrier: Vtu[buf] writes visible ---
    __syncthreads();

    // --- PV: O += P(16x64) * V(64x64), swizzled V reads ---
    __builtin_amdgcn_s_setprio(1);
#pragma unroll
    for (int kc = 0; kc < 2; ++kc) {
      const short8 pf = __builtin_bit_cast(short8, *(const uint4v*)&Plu[w][r16][kc * 16 + g * 4]);
#pragma unroll
      for (int j = 0; j < 4; ++j) {
        const int h = (2 * j + (r16 >> 3)) & 7;
        const short8 vf = __builtin_bit_cast(short8,
            *(const uint4v*)&Vtu[buf][j * 16 + r16][4 * (((kc << 2) + g) ^ h)]);
        oacc[j] = __builtin_amdgcn_mfma_f32_16x16x32_bf16(pf, vf, oacc[j], 0, 0, 0);
      }
    }
    __builtin_amdgcn_s_setprio(0);
  }

  // --- finalize ---
  float lt = l_run + __shfl_xor(l_run, 16);
  lt = lt + __shfl_xor(lt, 32);
  const float li0 = 1.f / __shfl(lt, g * 4 + 0);
  const float li1 = 1.f / __shfl(lt, g * 4 + 1);
  const float li2 = 1.f / __shfl(lt, g * 4 + 2);
  const float li3 = 1.f / __shfl(lt, g * 4 + 3);
  const int b = bh >> 4, h = bh & 15;
#pragma unroll
  for (int j = 0; j < 4; ++j) {
    const int d = h * DK + j * 16 + r16;
    const int qr = q0 + g * 4;
    ctx[(size_t)(b * S_LEN + qr + 0) * EMB + d] = f2b(oacc[j][0] * li0);
    ctx[(size_t)(b * S_LEN + qr + 1) * EMB + d] = f2b(oacc[j][1] * li1);
    ctx[(size_t)(b * S_LEN + qr + 2) * EMB + d] = f2b(oacc[j][2] * li2);
    ctx[(size_t)(b * S_LEN + qr + 3) * EMB + d] = f2b(oacc[j][3] * li3);
  }
}

// ---------------------------------------------------------------------------
extern "C" void kernel_launch(void* const* d_in, const int* in_sizes, int n_in,
                              void* d_out, int out_size, void* d_ws, size_t ws_size,
                              hipStream_t stream)
{
  const float* q  = (const float*)d_in[0];
  const float* k  = (const float*)d_in[1];
  const float* v  = (const float*)d_in[2];
  const float* Wq = (const float*)d_in[3];
  const float* bq = (const float*)d_in[4];
  const float* Wk = (const float*)d_in[5];
  const float* bk = (const float*)d_in[6];
  const float* Wv = (const float*)d_in[7];
  const float* bv = (const float*)d_in[8];
  const float* Wo = (const float*)d_in[9];
  const float* bo = (const float*)d_in[10];

  short* ws = (short*)d_ws;
  const size_t WSZ  = (size_t)EMB * EMB;   // 1M elems per weight matrix
  const size_t PROJ = (size_t)MTOT * EMB;  // 4M elems per activation
  short* Wb  = ws;                 // bf16 weights: Wq,Wk,Wv consecutive + Wo
  short* Wob = ws + 3 * WSZ;
  short* Qp  = ws + 4 * WSZ;       // (B,H,S,DK) bf16, pre-scaled
  short* Vp  = Qp + PROJ;
  short* Cx  = Vp + PROJ;          // (B*S, E) bf16 context
  short* Kp  = (short*)d_out;      // K parks in d_out; consumed before final GEMM

  cvt_w4<<<dim3((int)(WSZ / 4 / 256), 4), dim3(256), 0, stream>>>(Wq, Wk, Wv, Wo, ws);

  gemm_qkv<<<dim3(768), dim3(256), 0, stream>>>(q, k, v, Wb, bq, bk, bv, Qp, Kp, Vp);
  attn_kernel<<<dim3(1024), dim3(256), 0, stream>>>(Qp, Kp, Vp, Cx);
  gemm_out<<<dim3(256), dim3(256), 0, stream>>>(Cx, Wob, bo, (float*)d_out);
}

// Round 9
// 172.080 us; speedup vs baseline: 1.7068x; 1.3069x over previous
//
#include <hip/hip_runtime.h>
#include <stdint.h>

// Problem constants
#define S_LEN 2048
#define EMB   1024
#define NH    16
#define DK    64
#define BATCH 2
#define MTOT  (BATCH * S_LEN)  // 4096

typedef __attribute__((ext_vector_type(8))) short    short8;
typedef __attribute__((ext_vector_type(4))) float    f32x4;
typedef __attribute__((ext_vector_type(4))) float    float4v;
typedef __attribute__((ext_vector_type(4))) unsigned uint4v;
typedef __attribute__((ext_vector_type(2))) unsigned uint2v;

__device__ __forceinline__ short f2b(float f) {
  unsigned u = __builtin_bit_cast(unsigned, f);
  u = (u + 0x7FFFu + ((u >> 16) & 1u)) >> 16;  // RNE to bf16
  return (short)u;
}
// pack two f32 -> two bf16 in one uint (low = a, high = b)
__device__ __forceinline__ unsigned cvt2(float a, float b) {
  unsigned r;
  asm("v_cvt_pk_bf16_f32 %0, %1, %2" : "=v"(r) : "v"(a), "v"(b));
  return r;
}

// ---------------------------------------------------------------------------
// Fused f32 -> bf16 weight convert: grid (WSZ/4/256, 4), y picks the matrix.
// ---------------------------------------------------------------------------
__global__ __launch_bounds__(256) void cvt_w4(const float* __restrict__ w0,
                                              const float* __restrict__ w1,
                                              const float* __restrict__ w2,
                                              const float* __restrict__ w3,
                                              short* __restrict__ dst)
{
  const size_t WSZ = (size_t)EMB * EMB;
  const int y = blockIdx.y;
  const float* src = (y == 0) ? w0 : (y == 1) ? w1 : (y == 2) ? w2 : w3;
  short* d = dst + (size_t)y * WSZ;
  const int i = blockIdx.x * 256 + threadIdx.x;  // exact cover, no tail
  const f32x4 v = *(const f32x4*)(src + (size_t)i * 4);
  uint2v p;
  p[0] = cvt2(v[0], v[1]);
  p[1] = cvt2(v[2], v[3]);
  *(uint2v*)(d + (size_t)i * 4) = p;
}

// ---------------------------------------------------------------------------
// Shared NT-GEMM body, software-pipelined staging (unchanged from round 8):
//   prologue: load tile 0 into regs
//   loop:     barrier; regs -> LDS; barrier; issue loads for tile k+1;
//             16 MFMAs on LDS tile k  (loads land under the MFMA block)
// Tile 128x128, BK=64, 256 threads (4 waves 2x2, wave 64x64 = 4x4 frags).
// MODE 0: A = f32 (cvt to bf16 at LDS-write); out = bf16 scattered (B,H,S,DK).
// MODE 1: A = bf16; out = f32 row-major (M,N).
// ---------------------------------------------------------------------------
template <int MODE>
__device__ __forceinline__ void gemm_body(const float* __restrict__ Af0,
                                          const short* __restrict__ Ab0,
                                          const short* __restrict__ W,
                                          const float* __restrict__ bias,
                                          short* __restrict__ outb,
                                          float* __restrict__ outf,
                                          float scale, int m0, int n0)
{
  __shared__ __align__(16) unsigned Au[8][128][4];  // 16 KB
  __shared__ __align__(16) unsigned Bu[8][128][4];  // 16 KB
  const int tid = threadIdx.x;
  const int w = tid >> 6, l = tid & 63;
  const int g = l >> 4, r16 = l & 15;
  const int wr = w >> 1, wc = w & 1;
  const int srow = tid >> 3, shc = tid & 7;

  float4v acc[4][4];
#pragma unroll
  for (int i = 0; i < 4; ++i)
#pragma unroll
    for (int j = 0; j < 4; ++j)
      acc[i][j] = (float4v){0.f, 0.f, 0.f, 0.f};

  const float* Af = Af0 + (size_t)m0 * EMB;
  const short* Ab = Ab0 + (size_t)m0 * EMB;
  const short* Wbase = W + (size_t)n0 * EMB;

  f32x4  ax[4][2];   // MODE 0 raw A staging regs
  uint4v apk[4];     // MODE 1 A staging regs
  uint4v bpk[4];     // W staging regs

  // --- prologue: load tile k0 = 0 ---
#pragma unroll
  for (int p = 0; p < 4; ++p) {
    if constexpr (MODE == 0) {
      const float* src = Af + (size_t)(p * 32 + srow) * EMB + shc * 8;
      ax[p][0] = *(const f32x4*)src;
      ax[p][1] = *(const f32x4*)(src + 4);
    } else {
      apk[p] = __builtin_bit_cast(uint4v,
          *(const short8*)(Ab + (size_t)(p * 32 + srow) * EMB + shc * 8));
    }
    bpk[p] = __builtin_bit_cast(uint4v,
        *(const short8*)(Wbase + (size_t)(p * 32 + srow) * EMB + shc * 8));
  }

  for (int k0 = 0; k0 < EMB; k0 += 64) {
    uint4v awr[4], bwr[4];
#pragma unroll
    for (int p = 0; p < 4; ++p) {
      if constexpr (MODE == 0) {
        awr[p][0] = cvt2(ax[p][0][0], ax[p][0][1]);
        awr[p][1] = cvt2(ax[p][0][2], ax[p][0][3]);
        awr[p][2] = cvt2(ax[p][1][0], ax[p][1][1]);
        awr[p][3] = cvt2(ax[p][1][2], ax[p][1][3]);
      } else {
        awr[p] = apk[p];
      }
      bwr[p] = bpk[p];
    }

    __syncthreads();   // previous tile's MFMAs done with LDS
#pragma unroll
    for (int p = 0; p < 4; ++p)
      *(uint4v*)&Au[shc][p * 32 + srow][0] = awr[p];
#pragma unroll
    for (int p = 0; p < 4; ++p)
      *(uint4v*)&Bu[shc][p * 32 + srow][0] = bwr[p];
    __syncthreads();   // tile k0 visible

    if (k0 + 64 < EMB) {
      const int kn = k0 + 64;
#pragma unroll
      for (int p = 0; p < 4; ++p) {
        if constexpr (MODE == 0) {
          const float* src = Af + (size_t)(p * 32 + srow) * EMB + kn + shc * 8;
          ax[p][0] = *(const f32x4*)src;
          ax[p][1] = *(const f32x4*)(src + 4);
        } else {
          apk[p] = __builtin_bit_cast(uint4v,
              *(const short8*)(Ab + (size_t)(p * 32 + srow) * EMB + kn + shc * 8));
        }
        bpk[p] = __builtin_bit_cast(uint4v,
            *(const short8*)(Wbase + (size_t)(p * 32 + srow) * EMB + kn + shc * 8));
      }
    }

    __builtin_amdgcn_s_setprio(1);
#pragma unroll
    for (int ks = 0; ks < 2; ++ks) {
      const int c = ks * 4 + g;
      short8 af[4], bf[4];
#pragma unroll
      for (int i = 0; i < 4; ++i)
        af[i] = __builtin_bit_cast(short8, *(const uint4v*)&Au[c][wr * 64 + i * 16 + r16][0]);
#pragma unroll
      for (int j = 0; j < 4; ++j)
        bf[j] = __builtin_bit_cast(short8, *(const uint4v*)&Bu[c][wc * 64 + j * 16 + r16][0]);
#pragma unroll
      for (int i = 0; i < 4; ++i)
#pragma unroll
        for (int j = 0; j < 4; ++j)
          acc[i][j] = __builtin_amdgcn_mfma_f32_16x16x32_bf16(af[i], bf[j], acc[i][j], 0, 0, 0);
    }
    __builtin_amdgcn_s_setprio(0);
  }

  // Epilogue: C/D layout col = l&15, row = (l>>4)*4 + r
#pragma unroll
  for (int j = 0; j < 4; ++j) {
    const int n = n0 + wc * 64 + j * 16 + r16;
    const float bv = bias[n];
#pragma unroll
    for (int i = 0; i < 4; ++i) {
#pragma unroll
      for (int r = 0; r < 4; ++r) {
        const int m = m0 + wr * 64 + i * 16 + g * 4 + r;
        const float vv = (acc[i][j][r] + bv) * scale;
        if constexpr (MODE == 0) {
          const int b = m >> 11, s = m & (S_LEN - 1);
          const int h = n >> 6, d = n & (DK - 1);
          outb[(size_t)((b * NH + h) * S_LEN + s) * DK + d] = f2b(vv);
        } else {
          outf[(size_t)m * EMB + n] = vv;
        }
      }
    }
  }
}

// Fused Q/K/V projections: grid 768 blocks.
// Q output pre-scaled by (1/sqrt(dk)) * log2(e) for exp2-domain softmax.
__global__ __launch_bounds__(256, 2) void gemm_qkv(const float* __restrict__ q,
                                                   const float* __restrict__ k,
                                                   const float* __restrict__ v,
                                                   const short* __restrict__ Wb,
                                                   const float* __restrict__ bq,
                                                   const float* __restrict__ bk,
                                                   const float* __restrict__ bv,
                                                   short* __restrict__ Qp,
                                                   short* __restrict__ Kp,
                                                   short* __restrict__ Vp)
{
  const int which = blockIdx.x >> 8;
  const int inner = blockIdx.x & 255;
  const int lin = (inner & 7) * 32 + (inner >> 3);  // XCD swizzle
  const int m0 = (lin >> 3) * 128, n0 = (lin & 7) * 128;
  const float* A    = (which == 0) ? q  : (which == 1) ? k  : v;
  const float* bias = (which == 0) ? bq : (which == 1) ? bk : bv;
  short* out        = (which == 0) ? Qp : (which == 1) ? Kp : Vp;
  const short* W = Wb + (size_t)which * EMB * EMB;
  const float scale = (which == 0) ? 0.125f * 1.44269504088896f : 1.0f;
  gemm_body<0>(A, nullptr, W, bias, out, nullptr, scale, m0, n0);
}

__global__ __launch_bounds__(256, 2) void gemm_out(const short* __restrict__ Cx,
                                                   const short* __restrict__ Wob,
                                                   const float* __restrict__ bo,
                                                   float* __restrict__ outp)
{
  const int lin = (blockIdx.x & 7) * 32 + (blockIdx.x >> 3);
  gemm_body<1>(nullptr, Cx, Wob, bo, nullptr, outp, 1.0f, (lin >> 3) * 128, (lin & 7) * 128);
}

// ---------------------------------------------------------------------------
// Flash attention, 32 q-rows per wave (two 16-row subtiles a/b sharing one
// K/V stream). Grid 512 XCD-swizzled (4 bh per XCD). Block 256 = 4 waves,
// QBLK = 128 rows/block.
//  - K-register fragments serve both subtiles (per-work VMEM halved)
//  - Vtu b128 PV reads shared by a/b MFMAs (per-work LDS-pipe load halved)
//  - exp2-domain softmax (scores pre-scaled by 0.125*log2e in Q projection),
//    independent a/b chains for in-wave ILP
//  - double-buffered V^T, ONE barrier/iter; setprio around MFMA clusters
// ---------------------------------------------------------------------------
__global__ __launch_bounds__(256, 2) void attn_kernel(const short* __restrict__ Qp,
                                                      const short* __restrict__ Kp,
                                                      const short* __restrict__ Vp,
                                                      short* __restrict__ ctx)
{
  __shared__ __align__(16) unsigned Vtu[2][64][36];     // 18432 B
  __shared__ __align__(16) unsigned Plu[4][2][16][36];  // 18432 B
  const int tid = threadIdx.x;
  const int w = tid >> 6, l = tid & 63;
  const int g = l >> 4, r16 = l & 15;
  const int lin = (blockIdx.x & 7) * 64 + (blockIdx.x >> 3);  // XCD swizzle
  const int bh = lin >> 4;                          // b*NH + h (4 per XCD)
  const int q0 = (lin & 15) * 128 + w * 32;         // wave's 32 q rows
  const short* Qb = Qp + (size_t)bh * S_LEN * DK;
  const short* Kb = Kp + (size_t)bh * S_LEN * DK;
  const short* Vb = Vp + (size_t)bh * S_LEN * DK;

  const short8 qf0a = *(const short8*)(Qb + (size_t)(q0 + r16) * DK + g * 8);
  const short8 qf1a = *(const short8*)(Qb + (size_t)(q0 + r16) * DK + 32 + g * 8);
  const short8 qf0b = *(const short8*)(Qb + (size_t)(q0 + 16 + r16) * DK + g * 8);
  const short8 qf1b = *(const short8*)(Qb + (size_t)(q0 + 16 + r16) * DK + 32 + g * 8);

  float4v oa[4], ob[4];
#pragma unroll
  for (int j = 0; j < 4; ++j) {
    oa[j] = (float4v){0.f, 0.f, 0.f, 0.f};
    ob[j] = (float4v){0.f, 0.f, 0.f, 0.f};
  }
  float m_a = -3.0e38f, l_a = 0.f, m_b = -3.0e38f, l_b = 0.f;

  // V loader: coalesced loads, swizzled LDS write (2-way banks = free)
  const int va  = tid >> 3;                 // kv pair 0..31
  const int vdb = (tid & 7) * 8;            // d base
  const int vcs = va ^ ((tid & 7) << 2);    // swizzled column

  // --- prefetch tile 0 ---
  short8 vr0 = *(const short8*)(Vb + (size_t)(2 * va) * DK + vdb);
  short8 vr1 = *(const short8*)(Vb + (size_t)(2 * va + 1) * DK + vdb);
  short8 kr0[4], kr1[4];
#pragma unroll
  for (int s = 0; s < 4; ++s) {
    kr0[s] = *(const short8*)(Kb + (size_t)(s * 16 + r16) * DK + g * 8);
    kr1[s] = *(const short8*)(Kb + (size_t)(s * 16 + r16) * DK + 32 + g * 8);
  }

  for (int t = 0; t < S_LEN / 64; ++t) {
    const int buf = t & 1;
    // --- stage V tile t (swizzled) ---
#pragma unroll
    for (int i = 0; i < 8; ++i) {
      const unsigned pk = ((unsigned)(unsigned short)vr0[i]) |
                          (((unsigned)(unsigned short)vr1[i]) << 16);
      Vtu[buf][vdb + i][vcs] = pk;
    }

    // --- QK^T both subtiles (register-only), shared K fragments ---
    float4v sa[4], sb[4];
    __builtin_amdgcn_s_setprio(1);
#pragma unroll
    for (int s = 0; s < 4; ++s) {
      float4v x = (float4v){0.f, 0.f, 0.f, 0.f};
      x = __builtin_amdgcn_mfma_f32_16x16x32_bf16(kr0[s], qf0a, x, 0, 0, 0);
      x = __builtin_amdgcn_mfma_f32_16x16x32_bf16(kr1[s], qf1a, x, 0, 0, 0);
      sa[s] = x;
      float4v y = (float4v){0.f, 0.f, 0.f, 0.f};
      y = __builtin_amdgcn_mfma_f32_16x16x32_bf16(kr0[s], qf0b, y, 0, 0, 0);
      y = __builtin_amdgcn_mfma_f32_16x16x32_bf16(kr1[s], qf1b, y, 0, 0, 0);
      sb[s] = y;
    }
    __builtin_amdgcn_s_setprio(0);

    // --- prefetch V,K for tile t+1 (wraps on last iter; harmless) ---
    const int nkv = ((t + 1) * 64) & (S_LEN - 1);
    vr0 = *(const short8*)(Vb + (size_t)(nkv + 2 * va) * DK + vdb);
    vr1 = *(const short8*)(Vb + (size_t)(nkv + 2 * va + 1) * DK + vdb);
#pragma unroll
    for (int s = 0; s < 4; ++s) {
      kr0[s] = *(const short8*)(Kb + (size_t)(nkv + s * 16 + r16) * DK + g * 8);
      kr1[s] = *(const short8*)(Kb + (size_t)(nkv + s * 16 + r16) * DK + 32 + g * 8);
    }

    // --- online softmax, exp2 domain, two independent chains ---
    float mxa[4], mxb[4];
#pragma unroll
    for (int s = 0; s < 4; ++s) {
      mxa[s] = fmaxf(fmaxf(sa[s][0], sa[s][1]), fmaxf(sa[s][2], sa[s][3]));
      mxb[s] = fmaxf(fmaxf(sb[s][0], sb[s][1]), fmaxf(sb[s][2], sb[s][3]));
    }
    float mta = fmaxf(fmaxf(mxa[0], mxa[1]), fmaxf(mxa[2], mxa[3]));
    float mtb = fmaxf(fmaxf(mxb[0], mxb[1]), fmaxf(mxb[2], mxb[3]));
    mta = fmaxf(mta, __shfl_xor(mta, 16));
    mtb = fmaxf(mtb, __shfl_xor(mtb, 16));
    mta = fmaxf(mta, __shfl_xor(mta, 32));
    mtb = fmaxf(mtb, __shfl_xor(mtb, 32));
    const float mna = fmaxf(m_a, mta);
    const float mnb = fmaxf(m_b, mtb);
    const float ala = exp2f(m_a - mna);
    const float alb = exp2f(m_b - mnb);
    float psa[4], psb[4];
#pragma unroll
    for (int s = 0; s < 4; ++s) {
      const float a0 = exp2f(sa[s][0] - mna), a1 = exp2f(sa[s][1] - mna);
      const float a2 = exp2f(sa[s][2] - mna), a3 = exp2f(sa[s][3] - mna);
      sa[s][0] = a0; sa[s][1] = a1; sa[s][2] = a2; sa[s][3] = a3;
      psa[s] = (a0 + a1) + (a2 + a3);
      const float b0 = exp2f(sb[s][0] - mnb), b1 = exp2f(sb[s][1] - mnb);
      const float b2 = exp2f(sb[s][2] - mnb), b3 = exp2f(sb[s][3] - mnb);
      sb[s][0] = b0; sb[s][1] = b1; sb[s][2] = b2; sb[s][3] = b3;
      psb[s] = (b0 + b1) + (b2 + b3);
    }
    l_a = l_a * ala + ((psa[0] + psa[1]) + (psa[2] + psa[3]));
    l_b = l_b * alb + ((psb[0] + psb[1]) + (psb[2] + psb[3]));
    m_a = mna; m_b = mnb;

    // --- P -> per-wave LDS (bf16 pairs; same-wave RAW, no barrier) ---
#pragma unroll
    for (int s = 0; s < 4; ++s) {
      Plu[w][0][r16][s * 8 + g * 2]     = cvt2(sa[s][0], sa[s][1]);
      Plu[w][0][r16][s * 8 + g * 2 + 1] = cvt2(sa[s][2], sa[s][3]);
      Plu[w][1][r16][s * 8 + g * 2]     = cvt2(sb[s][0], sb[s][1]);
      Plu[w][1][r16][s * 8 + g * 2 + 1] = cvt2(sb[s][2], sb[s][3]);
    }

    // --- rescale O by alpha (both subtiles) ---
    const float aa0 = __shfl(ala, g * 4 + 0), ab0 = __shfl(alb, g * 4 + 0);
    const float aa1 = __shfl(ala, g * 4 + 1), ab1 = __shfl(alb, g * 4 + 1);
    const float aa2 = __shfl(ala, g * 4 + 2), ab2 = __shfl(alb, g * 4 + 2);
    const float aa3 = __shfl(ala, g * 4 + 3), ab3 = __shfl(alb, g * 4 + 3);
#pragma unroll
    for (int j = 0; j < 4; ++j) {
      oa[j][0] *= aa0; oa[j][1] *= aa1; oa[j][2] *= aa2; oa[j][3] *= aa3;
      ob[j][0] *= ab0; ob[j][1] *= ab1; ob[j][2] *= ab2; ob[j][3] *= ab3;
    }

    // --- single barrier: Vtu[buf] writes visible ---
    __syncthreads();

    // --- PV: both subtiles share each Vtu b128 read ---
    __builtin_amdgcn_s_setprio(1);
#pragma unroll
    for (int kc = 0; kc < 2; ++kc) {
      const short8 pfa = __builtin_bit_cast(short8, *(const uint4v*)&Plu[w][0][r16][kc * 16 + g * 4]);
      const short8 pfb = __builtin_bit_cast(short8, *(const uint4v*)&Plu[w][1][r16][kc * 16 + g * 4]);
#pragma unroll
      for (int j = 0; j < 4; ++j) {
        const int h = (2 * j + (r16 >> 3)) & 7;
        const short8 vf = __builtin_bit_cast(short8,
            *(const uint4v*)&Vtu[buf][j * 16 + r16][4 * (((kc << 2) + g) ^ h)]);
        oa[j] = __builtin_amdgcn_mfma_f32_16x16x32_bf16(pfa, vf, oa[j], 0, 0, 0);
        ob[j] = __builtin_amdgcn_mfma_f32_16x16x32_bf16(pfb, vf, ob[j], 0, 0, 0);
      }
    }
    __builtin_amdgcn_s_setprio(0);
  }

  // --- finalize both subtiles ---
  float lta = l_a + __shfl_xor(l_a, 16);
  float ltb = l_b + __shfl_xor(l_b, 16);
  lta = lta + __shfl_xor(lta, 32);
  ltb = ltb + __shfl_xor(ltb, 32);
  const float lia0 = 1.f / __shfl(lta, g * 4 + 0), lib0 = 1.f / __shfl(ltb, g * 4 + 0);
  const float lia1 = 1.f / __shfl(lta, g * 4 + 1), lib1 = 1.f / __shfl(ltb, g * 4 + 1);
  const float lia2 = 1.f / __shfl(lta, g * 4 + 2), lib2 = 1.f / __shfl(ltb, g * 4 + 2);
  const float lia3 = 1.f / __shfl(lta, g * 4 + 3), lib3 = 1.f / __shfl(ltb, g * 4 + 3);
  const int b = bh >> 4, h = bh & 15;
#pragma unroll
  for (int j = 0; j < 4; ++j) {
    const int d = h * DK + j * 16 + r16;
    const int qa = q0 + g * 4;
    const int qb2 = q0 + 16 + g * 4;
    ctx[(size_t)(b * S_LEN + qa + 0) * EMB + d] = f2b(oa[j][0] * lia0);
    ctx[(size_t)(b * S_LEN + qa + 1) * EMB + d] = f2b(oa[j][1] * lia1);
    ctx[(size_t)(b * S_LEN + qa + 2) * EMB + d] = f2b(oa[j][2] * lia2);
    ctx[(size_t)(b * S_LEN + qa + 3) * EMB + d] = f2b(oa[j][3] * lia3);
    ctx[(size_t)(b * S_LEN + qb2 + 0) * EMB + d] = f2b(ob[j][0] * lib0);
    ctx[(size_t)(b * S_LEN + qb2 + 1) * EMB + d] = f2b(ob[j][1] * lib1);
    ctx[(size_t)(b * S_LEN + qb2 + 2) * EMB + d] = f2b(ob[j][2] * lib2);
    ctx[(size_t)(b * S_LEN + qb2 + 3) * EMB + d] = f2b(ob[j][3] * lib3);
  }
}

// ---------------------------------------------------------------------------
extern "C" void kernel_launch(void* const* d_in, const int* in_sizes, int n_in,
                              void* d_out, int out_size, void* d_ws, size_t ws_size,
                              hipStream_t stream)
{
  const float* q  = (const float*)d_in[0];
  const float* k  = (const float*)d_in[1];
  const float* v  = (const float*)d_in[2];
  const float* Wq = (const float*)d_in[3];
  const float* bq = (const float*)d_in[4];
  const float* Wk = (const float*)d_in[5];
  const float* bk = (const float*)d_in[6];
  const float* Wv = (const float*)d_in[7];
  const float* bv = (const float*)d_in[8];
  const float* Wo = (const float*)d_in[9];
  const float* bo = (const float*)d_in[10];

  short* ws = (short*)d_ws;
  const size_t WSZ  = (size_t)EMB * EMB;   // 1M elems per weight matrix
  const size_t PROJ = (size_t)MTOT * EMB;  // 4M elems per activation
  short* Wb  = ws;                 // bf16 weights: Wq,Wk,Wv consecutive + Wo
  short* Wob = ws + 3 * WSZ;
  short* Qp  = ws + 4 * WSZ;       // (B,H,S,DK) bf16, pre-scaled
  short* Vp  = Qp + PROJ;
  short* Cx  = Vp + PROJ;          // (B*S, E) bf16 context
  short* Kp  = (short*)d_out;      // K parks in d_out; consumed before final GEMM

  cvt_w4<<<dim3((int)(WSZ / 4 / 256), 4), dim3(256), 0, stream>>>(Wq, Wk, Wv, Wo, ws);

  gemm_qkv<<<dim3(768), dim3(256), 0, stream>>>(q, k, v, Wb, bq, bk, bv, Qp, Kp, Vp);
  attn_kernel<<<dim3(512), dim3(256), 0, stream>>>(Qp, Kp, Vp, Cx);
  gemm_out<<<dim3(256), dim3(256), 0, stream>>>(Cx, Wob, bo, (float*)d_out);
}

// Round 10
// 168.239 us; speedup vs baseline: 1.7458x; 1.0228x over previous
//
#include <hip/hip_runtime.h>
#include <stdint.h>

// Problem constants
#define S_LEN 2048
#define EMB   1024
#define NH    16
#define DK    64
#define BATCH 2
#define MTOT  (BATCH * S_LEN)  // 4096

typedef __attribute__((ext_vector_type(8))) short    short8;
typedef __attribute__((ext_vector_type(4))) float    f32x4;
typedef __attribute__((ext_vector_type(4))) float    float4v;
typedef __attribute__((ext_vector_type(4))) unsigned uint4v;
typedef __attribute__((ext_vector_type(2))) unsigned uint2v;

__device__ __forceinline__ short f2b(float f) {
  unsigned u = __builtin_bit_cast(unsigned, f);
  u = (u + 0x7FFFu + ((u >> 16) & 1u)) >> 16;  // RNE to bf16
  return (short)u;
}
// pack two f32 -> two bf16 in one uint (low = a, high = b)
__device__ __forceinline__ unsigned cvt2(float a, float b) {
  unsigned r;
  asm("v_cvt_pk_bf16_f32 %0, %1, %2" : "=v"(r) : "v"(a), "v"(b));
  return r;
}

// ---------------------------------------------------------------------------
// Fused f32 -> bf16 weight convert: grid (WSZ/4/256, 4), y picks the matrix.
// ---------------------------------------------------------------------------
__global__ __launch_bounds__(256) void cvt_w4(const float* __restrict__ w0,
                                              const float* __restrict__ w1,
                                              const float* __restrict__ w2,
                                              const float* __restrict__ w3,
                                              short* __restrict__ dst)
{
  const size_t WSZ = (size_t)EMB * EMB;
  const int y = blockIdx.y;
  const float* src = (y == 0) ? w0 : (y == 1) ? w1 : (y == 2) ? w2 : w3;
  short* d = dst + (size_t)y * WSZ;
  const int i = blockIdx.x * 256 + threadIdx.x;  // exact cover, no tail
  const f32x4 v = *(const f32x4*)(src + (size_t)i * 4);
  uint2v p;
  p[0] = cvt2(v[0], v[1]);
  p[1] = cvt2(v[2], v[3]);
  *(uint2v*)(d + (size_t)i * 4) = p;
}

// ---------------------------------------------------------------------------
// Shared NT-GEMM body, software-pipelined staging (unchanged from round 8):
//   prologue: load tile 0 into regs
//   loop:     barrier; regs -> LDS; barrier; issue loads for tile k+1;
//             16 MFMAs on LDS tile k  (loads land under the MFMA block)
// Tile 128x128, BK=64, 256 threads (4 waves 2x2, wave 64x64 = 4x4 frags).
// MODE 0: A = f32 (cvt to bf16 at LDS-write); out = bf16 scattered (B,H,S,DK).
// MODE 1: A = bf16; out = f32 row-major (M,N).
// ---------------------------------------------------------------------------
template <int MODE>
__device__ __forceinline__ void gemm_body(const float* __restrict__ Af0,
                                          const short* __restrict__ Ab0,
                                          const short* __restrict__ W,
                                          const float* __restrict__ bias,
                                          short* __restrict__ outb,
                                          float* __restrict__ outf,
                                          float scale, int m0, int n0)
{
  __shared__ __align__(16) unsigned Au[8][128][4];  // 16 KB
  __shared__ __align__(16) unsigned Bu[8][128][4];  // 16 KB
  const int tid = threadIdx.x;
  const int w = tid >> 6, l = tid & 63;
  const int g = l >> 4, r16 = l & 15;
  const int wr = w >> 1, wc = w & 1;
  const int srow = tid >> 3, shc = tid & 7;

  float4v acc[4][4];
#pragma unroll
  for (int i = 0; i < 4; ++i)
#pragma unroll
    for (int j = 0; j < 4; ++j)
      acc[i][j] = (float4v){0.f, 0.f, 0.f, 0.f};

  const float* Af = Af0 + (size_t)m0 * EMB;
  const short* Ab = Ab0 + (size_t)m0 * EMB;
  const short* Wbase = W + (size_t)n0 * EMB;

  f32x4  ax[4][2];   // MODE 0 raw A staging regs
  uint4v apk[4];     // MODE 1 A staging regs
  uint4v bpk[4];     // W staging regs

  // --- prologue: load tile k0 = 0 ---
#pragma unroll
  for (int p = 0; p < 4; ++p) {
    if constexpr (MODE == 0) {
      const float* src = Af + (size_t)(p * 32 + srow) * EMB + shc * 8;
      ax[p][0] = *(const f32x4*)src;
      ax[p][1] = *(const f32x4*)(src + 4);
    } else {
      apk[p] = __builtin_bit_cast(uint4v,
          *(const short8*)(Ab + (size_t)(p * 32 + srow) * EMB + shc * 8));
    }
    bpk[p] = __builtin_bit_cast(uint4v,
        *(const short8*)(Wbase + (size_t)(p * 32 + srow) * EMB + shc * 8));
  }

  for (int k0 = 0; k0 < EMB; k0 += 64) {
    uint4v awr[4], bwr[4];
#pragma unroll
    for (int p = 0; p < 4; ++p) {
      if constexpr (MODE == 0) {
        awr[p][0] = cvt2(ax[p][0][0], ax[p][0][1]);
        awr[p][1] = cvt2(ax[p][0][2], ax[p][0][3]);
        awr[p][2] = cvt2(ax[p][1][0], ax[p][1][1]);
        awr[p][3] = cvt2(ax[p][1][2], ax[p][1][3]);
      } else {
        awr[p] = apk[p];
      }
      bwr[p] = bpk[p];
    }

    __syncthreads();   // previous tile's MFMAs done with LDS
#pragma unroll
    for (int p = 0; p < 4; ++p)
      *(uint4v*)&Au[shc][p * 32 + srow][0] = awr[p];
#pragma unroll
    for (int p = 0; p < 4; ++p)
      *(uint4v*)&Bu[shc][p * 32 + srow][0] = bwr[p];
    __syncthreads();   // tile k0 visible

    if (k0 + 64 < EMB) {
      const int kn = k0 + 64;
#pragma unroll
      for (int p = 0; p < 4; ++p) {
        if constexpr (MODE == 0) {
          const float* src = Af + (size_t)(p * 32 + srow) * EMB + kn + shc * 8;
          ax[p][0] = *(const f32x4*)src;
          ax[p][1] = *(const f32x4*)(src + 4);
        } else {
          apk[p] = __builtin_bit_cast(uint4v,
              *(const short8*)(Ab + (size_t)(p * 32 + srow) * EMB + kn + shc * 8));
        }
        bpk[p] = __builtin_bit_cast(uint4v,
            *(const short8*)(Wbase + (size_t)(p * 32 + srow) * EMB + kn + shc * 8));
      }
    }

    __builtin_amdgcn_s_setprio(1);
#pragma unroll
    for (int ks = 0; ks < 2; ++ks) {
      const int c = ks * 4 + g;
      short8 af[4], bf[4];
#pragma unroll
      for (int i = 0; i < 4; ++i)
        af[i] = __builtin_bit_cast(short8, *(const uint4v*)&Au[c][wr * 64 + i * 16 + r16][0]);
#pragma unroll
      for (int j = 0; j < 4; ++j)
        bf[j] = __builtin_bit_cast(short8, *(const uint4v*)&Bu[c][wc * 64 + j * 16 + r16][0]);
#pragma unroll
      for (int i = 0; i < 4; ++i)
#pragma unroll
        for (int j = 0; j < 4; ++j)
          acc[i][j] = __builtin_amdgcn_mfma_f32_16x16x32_bf16(af[i], bf[j], acc[i][j], 0, 0, 0);
    }
    __builtin_amdgcn_s_setprio(0);
  }

  // Epilogue: C/D layout col = l&15, row = (l>>4)*4 + r
#pragma unroll
  for (int j = 0; j < 4; ++j) {
    const int n = n0 + wc * 64 + j * 16 + r16;
    const float bv = bias[n];
#pragma unroll
    for (int i = 0; i < 4; ++i) {
#pragma unroll
      for (int r = 0; r < 4; ++r) {
        const int m = m0 + wr * 64 + i * 16 + g * 4 + r;
        const float vv = (acc[i][j][r] + bv) * scale;
        if constexpr (MODE == 0) {
          const int b = m >> 11, s = m & (S_LEN - 1);
          const int h = n >> 6, d = n & (DK - 1);
          outb[(size_t)((b * NH + h) * S_LEN + s) * DK + d] = f2b(vv);
        } else {
          outf[(size_t)m * EMB + n] = vv;
        }
      }
    }
  }
}

// Fused Q/K/V projections: grid 768 blocks.
// Q output pre-scaled by (1/sqrt(dk)) * log2(e) for exp2-domain softmax.
__global__ __launch_bounds__(256, 2) void gemm_qkv(const float* __restrict__ q,
                                                   const float* __restrict__ k,
                                                   const float* __restrict__ v,
                                                   const short* __restrict__ Wb,
                                                   const float* __restrict__ bq,
                                                   const float* __restrict__ bk,
                                                   const float* __restrict__ bv,
                                                   short* __restrict__ Qp,
                                                   short* __restrict__ Kp,
                                                   short* __restrict__ Vp)
{
  const int which = blockIdx.x >> 8;
  const int inner = blockIdx.x & 255;
  const int lin = (inner & 7) * 32 + (inner >> 3);  // XCD swizzle
  const int m0 = (lin >> 3) * 128, n0 = (lin & 7) * 128;
  const float* A    = (which == 0) ? q  : (which == 1) ? k  : v;
  const float* bias = (which == 0) ? bq : (which == 1) ? bk : bv;
  short* out        = (which == 0) ? Qp : (which == 1) ? Kp : Vp;
  const short* W = Wb + (size_t)which * EMB * EMB;
  const float scale = (which == 0) ? 0.125f * 1.44269504088896f : 1.0f;
  gemm_body<0>(A, nullptr, W, bias, out, nullptr, scale, m0, n0);
}

__global__ __launch_bounds__(256, 2) void gemm_out(const short* __restrict__ Cx,
                                                   const short* __restrict__ Wob,
                                                   const float* __restrict__ bo,
                                                   float* __restrict__ outp)
{
  const int lin = (blockIdx.x & 7) * 32 + (blockIdx.x >> 3);
  gemm_body<1>(nullptr, Cx, Wob, bo, nullptr, outp, 1.0f, (lin >> 3) * 128, (lin & 7) * 128);
}

// ---------------------------------------------------------------------------
// Flash attention, 32 q-rows per wave (two 16-row subtiles a/b sharing one
// K/V stream). Grid 512 XCD-swizzled. Block 256 = 4 waves, QBLK = 128.
//  - defer-max (THR=8, exp2 domain): when no lane's tile-max exceeds the
//    running max + 8, keep the old max -> skip cross-lane max reduces,
//    alpha, O/l rescale, broadcasts. Full path on growth (always at t=0).
//  - row-sum via MFMA ones-column: lacc = mfma(P, 1) accumulates softmax
//    denominators in C-layout rows (no psum adds, no final reduce).
//  - K frags shared by both subtiles; Vtu b128 reads shared by a/b MFMAs;
//    double-buffered V^T, ONE barrier/iter; setprio on MFMA clusters.
// ---------------------------------------------------------------------------
__global__ __launch_bounds__(256, 2) void attn_kernel(const short* __restrict__ Qp,
                                                      const short* __restrict__ Kp,
                                                      const short* __restrict__ Vp,
                                                      short* __restrict__ ctx)
{
  __shared__ __align__(16) unsigned Vtu[2][64][36];     // 18432 B
  __shared__ __align__(16) unsigned Plu[4][2][16][36];  // 18432 B
  const int tid = threadIdx.x;
  const int w = tid >> 6, l = tid & 63;
  const int g = l >> 4, r16 = l & 15;
  const int lin = (blockIdx.x & 7) * 64 + (blockIdx.x >> 3);  // XCD swizzle
  const int bh = lin >> 4;                          // b*NH + h (4 per XCD)
  const int q0 = (lin & 15) * 128 + w * 32;         // wave's 32 q rows
  const short* Qb = Qp + (size_t)bh * S_LEN * DK;
  const short* Kb = Kp + (size_t)bh * S_LEN * DK;
  const short* Vb = Vp + (size_t)bh * S_LEN * DK;

  const short8 qf0a = *(const short8*)(Qb + (size_t)(q0 + r16) * DK + g * 8);
  const short8 qf1a = *(const short8*)(Qb + (size_t)(q0 + r16) * DK + 32 + g * 8);
  const short8 qf0b = *(const short8*)(Qb + (size_t)(q0 + 16 + r16) * DK + g * 8);
  const short8 qf1b = *(const short8*)(Qb + (size_t)(q0 + 16 + r16) * DK + 32 + g * 8);

  // bf16 1.0 splat for the l-sum MFMA B operand
  const short one_b = (short)0x3F80;
  const short8 ones8 = {one_b, one_b, one_b, one_b, one_b, one_b, one_b, one_b};

  float4v oa[4], ob[4];
#pragma unroll
  for (int j = 0; j < 4; ++j) {
    oa[j] = (float4v){0.f, 0.f, 0.f, 0.f};
    ob[j] = (float4v){0.f, 0.f, 0.f, 0.f};
  }
  float4v lacc_a = (float4v){0.f, 0.f, 0.f, 0.f};
  float4v lacc_b = (float4v){0.f, 0.f, 0.f, 0.f};
  float m_a = -3.0e38f, m_b = -3.0e38f;   // per-lane running max of q = l&15

  // V loader: coalesced loads, swizzled LDS write (2-way banks = free)
  const int va  = tid >> 3;                 // kv pair 0..31
  const int vdb = (tid & 7) * 8;            // d base
  const int vcs = va ^ ((tid & 7) << 2);    // swizzled column

  // --- prefetch tile 0 ---
  short8 vr0 = *(const short8*)(Vb + (size_t)(2 * va) * DK + vdb);
  short8 vr1 = *(const short8*)(Vb + (size_t)(2 * va + 1) * DK + vdb);
  short8 kr0[4], kr1[4];
#pragma unroll
  for (int s = 0; s < 4; ++s) {
    kr0[s] = *(const short8*)(Kb + (size_t)(s * 16 + r16) * DK + g * 8);
    kr1[s] = *(const short8*)(Kb + (size_t)(s * 16 + r16) * DK + 32 + g * 8);
  }

  for (int t = 0; t < S_LEN / 64; ++t) {
    const int buf = t & 1;
    // --- stage V tile t (swizzled) ---
#pragma unroll
    for (int i = 0; i < 8; ++i) {
      const unsigned pk = ((unsigned)(unsigned short)vr0[i]) |
                          (((unsigned)(unsigned short)vr1[i]) << 16);
      Vtu[buf][vdb + i][vcs] = pk;
    }

    // --- QK^T both subtiles (register-only), shared K fragments ---
    float4v sa[4], sb[4];
    __builtin_amdgcn_s_setprio(1);
#pragma unroll
    for (int s = 0; s < 4; ++s) {
      float4v x = (float4v){0.f, 0.f, 0.f, 0.f};
      x = __builtin_amdgcn_mfma_f32_16x16x32_bf16(kr0[s], qf0a, x, 0, 0, 0);
      x = __builtin_amdgcn_mfma_f32_16x16x32_bf16(kr1[s], qf1a, x, 0, 0, 0);
      sa[s] = x;
      float4v y = (float4v){0.f, 0.f, 0.f, 0.f};
      y = __builtin_amdgcn_mfma_f32_16x16x32_bf16(kr0[s], qf0b, y, 0, 0, 0);
      y = __builtin_amdgcn_mfma_f32_16x16x32_bf16(kr1[s], qf1b, y, 0, 0, 0);
      sb[s] = y;
    }
    __builtin_amdgcn_s_setprio(0);

    // --- prefetch V,K for tile t+1 (wraps on last iter; harmless) ---
    const int nkv = ((t + 1) * 64) & (S_LEN - 1);
    vr0 = *(const short8*)(Vb + (size_t)(nkv + 2 * va) * DK + vdb);
    vr1 = *(const short8*)(Vb + (size_t)(nkv + 2 * va + 1) * DK + vdb);
#pragma unroll
    for (int s = 0; s < 4; ++s) {
      kr0[s] = *(const short8*)(Kb + (size_t)(nkv + s * 16 + r16) * DK + g * 8);
      kr1[s] = *(const short8*)(Kb + (size_t)(nkv + s * 16 + r16) * DK + 32 + g * 8);
    }

    // --- per-lane tile max (in-lane trees; lane's q = l&15) ---
    float mxa[4], mxb[4];
#pragma unroll
    for (int s = 0; s < 4; ++s) {
      mxa[s] = fmaxf(fmaxf(sa[s][0], sa[s][1]), fmaxf(sa[s][2], sa[s][3]));
      mxb[s] = fmaxf(fmaxf(sb[s][0], sb[s][1]), fmaxf(sb[s][2], sb[s][3]));
    }
    const float mta_l = fmaxf(fmaxf(mxa[0], mxa[1]), fmaxf(mxa[2], mxa[3]));
    const float mtb_l = fmaxf(fmaxf(mxb[0], mxb[1]), fmaxf(mxb[2], mxb[3]));

    const int okk = (mta_l <= m_a + 8.f) && (mtb_l <= m_b + 8.f);
    if (__all(okk)) {
      // --- fast path: keep old max (P bounded by 2^8); no rescale ---
#pragma unroll
      for (int s = 0; s < 4; ++s) {
        const float a0 = exp2f(sa[s][0] - m_a), a1 = exp2f(sa[s][1] - m_a);
        const float a2 = exp2f(sa[s][2] - m_a), a3 = exp2f(sa[s][3] - m_a);
        Plu[w][0][r16][s * 8 + g * 2]     = cvt2(a0, a1);
        Plu[w][0][r16][s * 8 + g * 2 + 1] = cvt2(a2, a3);
        const float b0 = exp2f(sb[s][0] - m_b), b1 = exp2f(sb[s][1] - m_b);
        const float b2 = exp2f(sb[s][2] - m_b), b3 = exp2f(sb[s][3] - m_b);
        Plu[w][1][r16][s * 8 + g * 2]     = cvt2(b0, b1);
        Plu[w][1][r16][s * 8 + g * 2 + 1] = cvt2(b2, b3);
      }
    } else {
      // --- full path: cross-lane max, rescale O and l accumulators ---
      float mta = fmaxf(mta_l, __shfl_xor(mta_l, 16));
      float mtb = fmaxf(mtb_l, __shfl_xor(mtb_l, 16));
      mta = fmaxf(mta, __shfl_xor(mta, 32));
      mtb = fmaxf(mtb, __shfl_xor(mtb, 32));
      const float mna = fmaxf(m_a, mta);
      const float mnb = fmaxf(m_b, mtb);
      const float ala = exp2f(m_a - mna);
      const float alb = exp2f(m_b - mnb);
      const float aa0 = __shfl(ala, g * 4 + 0), ab0 = __shfl(alb, g * 4 + 0);
      const float aa1 = __shfl(ala, g * 4 + 1), ab1 = __shfl(alb, g * 4 + 1);
      const float aa2 = __shfl(ala, g * 4 + 2), ab2 = __shfl(alb, g * 4 + 2);
      const float aa3 = __shfl(ala, g * 4 + 3), ab3 = __shfl(alb, g * 4 + 3);
#pragma unroll
      for (int j = 0; j < 4; ++j) {
        oa[j][0] *= aa0; oa[j][1] *= aa1; oa[j][2] *= aa2; oa[j][3] *= aa3;
        ob[j][0] *= ab0; ob[j][1] *= ab1; ob[j][2] *= ab2; ob[j][3] *= ab3;
      }
      lacc_a[0] *= aa0; lacc_a[1] *= aa1; lacc_a[2] *= aa2; lacc_a[3] *= aa3;
      lacc_b[0] *= ab0; lacc_b[1] *= ab1; lacc_b[2] *= ab2; lacc_b[3] *= ab3;
#pragma unroll
      for (int s = 0; s < 4; ++s) {
        const float a0 = exp2f(sa[s][0] - mna), a1 = exp2f(sa[s][1] - mna);
        const float a2 = exp2f(sa[s][2] - mna), a3 = exp2f(sa[s][3] - mna);
        Plu[w][0][r16][s * 8 + g * 2]     = cvt2(a0, a1);
        Plu[w][0][r16][s * 8 + g * 2 + 1] = cvt2(a2, a3);
        const float b0 = exp2f(sb[s][0] - mnb), b1 = exp2f(sb[s][1] - mnb);
        const float b2 = exp2f(sb[s][2] - mnb), b3 = exp2f(sb[s][3] - mnb);
        Plu[w][1][r16][s * 8 + g * 2]     = cvt2(b0, b1);
        Plu[w][1][r16][s * 8 + g * 2 + 1] = cvt2(b2, b3);
      }
      m_a = mna; m_b = mnb;
    }

    // --- single barrier: Vtu[buf] writes visible ---
    __syncthreads();

    // --- PV + l-sum: both subtiles share each Vtu b128 read ---
    __builtin_amdgcn_s_setprio(1);
#pragma unroll
    for (int kc = 0; kc < 2; ++kc) {
      const short8 pfa = __builtin_bit_cast(short8, *(const uint4v*)&Plu[w][0][r16][kc * 16 + g * 4]);
      const short8 pfb = __builtin_bit_cast(short8, *(const uint4v*)&Plu[w][1][r16][kc * 16 + g * 4]);
      lacc_a = __builtin_amdgcn_mfma_f32_16x16x32_bf16(pfa, ones8, lacc_a, 0, 0, 0);
      lacc_b = __builtin_amdgcn_mfma_f32_16x16x32_bf16(pfb, ones8, lacc_b, 0, 0, 0);
#pragma unroll
      for (int j = 0; j < 4; ++j) {
        const int h = (2 * j + (r16 >> 3)) & 7;
        const short8 vf = __builtin_bit_cast(short8,
            *(const uint4v*)&Vtu[buf][j * 16 + r16][4 * (((kc << 2) + g) ^ h)]);
        oa[j] = __builtin_amdgcn_mfma_f32_16x16x32_bf16(pfa, vf, oa[j], 0, 0, 0);
        ob[j] = __builtin_amdgcn_mfma_f32_16x16x32_bf16(pfb, vf, ob[j], 0, 0, 0);
      }
    }
    __builtin_amdgcn_s_setprio(0);
  }

  // --- finalize: lacc rows align with oacc C-layout rows ---
  const float ria0 = 1.f / lacc_a[0], rib0 = 1.f / lacc_b[0];
  const float ria1 = 1.f / lacc_a[1], rib1 = 1.f / lacc_b[1];
  const float ria2 = 1.f / lacc_a[2], rib2 = 1.f / lacc_b[2];
  const float ria3 = 1.f / lacc_a[3], rib3 = 1.f / lacc_b[3];
  const int b = bh >> 4, h = bh & 15;
#pragma unroll
  for (int j = 0; j < 4; ++j) {
    const int d = h * DK + j * 16 + r16;
    const int qa = q0 + g * 4;
    const int qb2 = q0 + 16 + g * 4;
    ctx[(size_t)(b * S_LEN + qa + 0) * EMB + d] = f2b(oa[j][0] * ria0);
    ctx[(size_t)(b * S_LEN + qa + 1) * EMB + d] = f2b(oa[j][1] * ria1);
    ctx[(size_t)(b * S_LEN + qa + 2) * EMB + d] = f2b(oa[j][2] * ria2);
    ctx[(size_t)(b * S_LEN + qa + 3) * EMB + d] = f2b(oa[j][3] * ria3);
    ctx[(size_t)(b * S_LEN + qb2 + 0) * EMB + d] = f2b(ob[j][0] * rib0);
    ctx[(size_t)(b * S_LEN + qb2 + 1) * EMB + d] = f2b(ob[j][1] * rib1);
    ctx[(size_t)(b * S_LEN + qb2 + 2) * EMB + d] = f2b(ob[j][2] * rib2);
    ctx[(size_t)(b * S_LEN + qb2 + 3) * EMB + d] = f2b(ob[j][3] * rib3);
  }
}

// ---------------------------------------------------------------------------
extern "C" void kernel_launch(void* const* d_in, const int* in_sizes, int n_in,
                              void* d_out, int out_size, void* d_ws, size_t ws_size,
                              hipStream_t stream)
{
  const float* q  = (const float*)d_in[0];
  const float* k  = (const float*)d_in[1];
  const float* v  = (const float*)d_in[2];
  const float* Wq = (const float*)d_in[3];
  const float* bq = (const float*)d_in[4];
  const float* Wk = (const float*)d_in[5];
  const float* bk = (const float*)d_in[6];
  const float* Wv = (const float*)d_in[7];
  const float* bv = (const float*)d_in[8];
  const float* Wo = (const float*)d_in[9];
  const float* bo = (const float*)d_in[10];

  short* ws = (short*)d_ws;
  const size_t WSZ  = (size_t)EMB * EMB;   // 1M elems per weight matrix
  const size_t PROJ = (size_t)MTOT * EMB;  // 4M elems per activation
  short* Wb  = ws;                 // bf16 weights: Wq,Wk,Wv consecutive + Wo
  short* Wob = ws + 3 * WSZ;
  short* Qp  = ws + 4 * WSZ;       // (B,H,S,DK) bf16, pre-scaled
  short* Vp  = Qp + PROJ;
  short* Cx  = Vp + PROJ;          // (B*S, E) bf16 context
  short* Kp  = (short*)d_out;      // K parks in d_out; consumed before final GEMM

  cvt_w4<<<dim3((int)(WSZ / 4 / 256), 4), dim3(256), 0, stream>>>(Wq, Wk, Wv, Wo, ws);

  gemm_qkv<<<dim3(768), dim3(256), 0, stream>>>(q, k, v, Wb, bq, bk, bv, Qp, Kp, Vp);
  attn_kernel<<<dim3(512), dim3(256), 0, stream>>>(Qp, Kp, Vp, Cx);
  gemm_out<<<dim3(256), dim3(256), 0, stream>>>(Cx, Wob, bo, (float*)d_out);
}